// Round 9
// baseline (1299.627 us; speedup 1.0000x reference)
//
#include <hip/hip_runtime.h>
#include <hip/hip_bf16.h>

#define N_NODESC 100000
#define N_EDGESC 1600000
#define N_GRAPHSC 200
#define IN_DIMC 25
#define HIDC 256
#define OUT_DIMC 128
#define SCAN_BLK 1024
#define SCAN_NBLK ((N_NODESC + SCAN_BLK - 1) / SCAN_BLK)
#define NRB ((N_NODESC + 127) / 128)  // 782 row-blocks

typedef __attribute__((ext_vector_type(8))) short bf16x8;
typedef __attribute__((ext_vector_type(4))) float f32x4;

// ---------- bf16 helpers (raw ushort storage) ----------
__device__ inline float bf2f(unsigned short u) {
    union { float f; unsigned u32; } c;
    c.u32 = ((unsigned)u) << 16;
    return c.f;
}
__device__ inline unsigned short f2bf(float f) {
    union { float f; unsigned u; } c;
    c.f = f;
    unsigned r = (c.u + 0x7FFFu + ((c.u >> 16) & 1u)) >> 16;  // RNE
    return (unsigned short)r;
}
__device__ inline float u2f(unsigned u) {
    union { unsigned u; float f; } c;
    c.u = u;
    return c.f;
}

// ---------- utility fills ----------
__global__ void fill_u32(unsigned* __restrict__ p, unsigned v, int n) {
    int i = blockIdx.x * 256 + threadIdx.x;
    if (i < n) p[i] = v;
}

// ---------- degree / inv ----------
__global__ void deg_kernel(const int* __restrict__ dst, int* __restrict__ cnt, int E) {
    int i = blockIdx.x * 256 + threadIdx.x;
    if (i < E) atomicAdd(&cnt[dst[i]], 1);
}
__global__ void inv_kernel(const int* __restrict__ cnt, float* __restrict__ inv, int n) {
    int i = blockIdx.x * 256 + threadIdx.x;
    if (i < n) inv[i] = 1.0f / (float)max(cnt[i], 1);
}

// ---------- hierarchical exclusive scan over cnt[N] -> ofs[N+1] ----------
__global__ __launch_bounds__(SCAN_BLK) void scan_partial(const int* __restrict__ cnt,
                                                         int* __restrict__ ofs,
                                                         int* __restrict__ bsum) {
    __shared__ int sm[SCAN_BLK];
    int i = blockIdx.x * SCAN_BLK + threadIdx.x;
    int v = (i < N_NODESC) ? cnt[i] : 0;
    sm[threadIdx.x] = v;
    __syncthreads();
    for (int off = 1; off < SCAN_BLK; off <<= 1) {
        int t = (threadIdx.x >= off) ? sm[threadIdx.x - off] : 0;
        __syncthreads();
        sm[threadIdx.x] += t;
        __syncthreads();
    }
    if (i < N_NODESC) ofs[i] = sm[threadIdx.x] - v;  // exclusive within block
    if (threadIdx.x == SCAN_BLK - 1) bsum[blockIdx.x] = sm[SCAN_BLK - 1];
}

__global__ __launch_bounds__(128) void scan_bsums(int* __restrict__ bsum) {
    __shared__ int sm[SCAN_NBLK];
    if (threadIdx.x == 0) {
        int run = 0;
        for (int b = 0; b < SCAN_NBLK; ++b) {
            int t = bsum[b];
            sm[b] = run;
            run += t;
        }
        for (int b = 0; b < SCAN_NBLK; ++b) bsum[b] = sm[b];
    }
}

__global__ __launch_bounds__(SCAN_BLK) void scan_add(int* __restrict__ ofs,
                                                     const int* __restrict__ bsum) {
    int i = blockIdx.x * SCAN_BLK + threadIdx.x;
    if (i < N_NODESC) ofs[i] += bsum[blockIdx.x];
    if (i == 0) ofs[N_NODESC] = N_EDGESC;
}

// ---------- CSR fill ----------
__global__ void csr_fill(const int* __restrict__ src, const int* __restrict__ dst,
                         const int* __restrict__ ofs, int* __restrict__ cursor,
                         int* __restrict__ csr, int E) {
    int e = blockIdx.x * 256 + threadIdx.x;
    if (e < E) {
        int d = dst[e];
        int pos = atomicAdd(&cursor[d], 1);
        csr[ofs[d] + pos] = src[e];
    }
}

// ---------- graph ranges: boundary scan (batch sorted; no atomics) ----------
__global__ void ranges_bounds(const int* __restrict__ batch, int* __restrict__ gstart,
                              int* __restrict__ gend, int n) {
    int i = blockIdx.x * 256 + threadIdx.x;
    if (i >= n) return;
    int g = batch[i];
    if (i == 0 || batch[i - 1] != g) gstart[g] = i;
    if (i == n - 1 || batch[i + 1] != g) gend[g] = i + 1;
}

// ---------- weight transpose f32[256][256] -> bf16 WT[n][k] ----------
__global__ void wtransT(const float* __restrict__ W, unsigned short* __restrict__ WT) {
    __shared__ float t[16][17];
    int bx = blockIdx.x, by = blockIdx.y;
    int tx = threadIdx.x & 15, ty = threadIdx.x >> 4;
    t[ty][tx] = W[(by * 16 + ty) * HIDC + bx * 16 + tx];
    __syncthreads();
    WT[(size_t)(bx * 16 + ty) * HIDC + by * 16 + tx] = f2bf(t[tx][ty]);
}

// ---------- layer-1 mean gather (f32, 25 channels) ----------
__global__ void gather25(const float* __restrict__ x, const int* __restrict__ ofs,
                         const int* __restrict__ csr, const float* __restrict__ inv,
                         float* __restrict__ agg) {
    int idx = blockIdx.x * 256 + threadIdx.x;
    int node = idx >> 5, c = idx & 31;
    if (node >= N_NODESC || c >= IN_DIMC) return;
    float acc = 0.0f;
    int s = ofs[node], e = ofs[node + 1];
    for (int j = s; j < e; ++j) acc += x[(size_t)csr[j] * IN_DIMC + c];
    agg[(size_t)node * IN_DIMC + c] = acc * inv[node];
}

// ---------- hidden mean gather: one wave/node, half-wave/edge, 16B lanes ----------
__global__ void gather256(const unsigned short* __restrict__ h, const int* __restrict__ ofs,
                          const int* __restrict__ csr, const float* __restrict__ inv,
                          unsigned short* __restrict__ agg) {
    long long gtid = (long long)blockIdx.x * 256 + threadIdx.x;
    int node = (int)(gtid >> 6);
    if (node >= N_NODESC) return;
    const int lane = threadIdx.x & 63;
    const int half = lane >> 5;
    const int l = lane & 31;
    const int s = ofs[node], e = ofs[node + 1];

    float a0 = 0, a1 = 0, a2 = 0, a3 = 0, a4 = 0, a5 = 0, a6 = 0, a7 = 0;
    const size_t coff = (size_t)l * 8;

    int j = s + half;
    for (; j + 2 < e; j += 4) {
        int sn0 = csr[j];
        int sn1 = csr[j + 2];
        int4 v0 = *reinterpret_cast<const int4*>(h + (size_t)sn0 * HIDC + coff);
        int4 v1 = *reinterpret_cast<const int4*>(h + (size_t)sn1 * HIDC + coff);
        a0 += u2f(((unsigned)v0.x) << 16); a1 += u2f(((unsigned)v0.x) & 0xffff0000u);
        a2 += u2f(((unsigned)v0.y) << 16); a3 += u2f(((unsigned)v0.y) & 0xffff0000u);
        a4 += u2f(((unsigned)v0.z) << 16); a5 += u2f(((unsigned)v0.z) & 0xffff0000u);
        a6 += u2f(((unsigned)v0.w) << 16); a7 += u2f(((unsigned)v0.w) & 0xffff0000u);
        a0 += u2f(((unsigned)v1.x) << 16); a1 += u2f(((unsigned)v1.x) & 0xffff0000u);
        a2 += u2f(((unsigned)v1.y) << 16); a3 += u2f(((unsigned)v1.y) & 0xffff0000u);
        a4 += u2f(((unsigned)v1.z) << 16); a5 += u2f(((unsigned)v1.z) & 0xffff0000u);
        a6 += u2f(((unsigned)v1.w) << 16); a7 += u2f(((unsigned)v1.w) & 0xffff0000u);
    }
    if (j < e) {
        int sn0 = csr[j];
        int4 v0 = *reinterpret_cast<const int4*>(h + (size_t)sn0 * HIDC + coff);
        a0 += u2f(((unsigned)v0.x) << 16); a1 += u2f(((unsigned)v0.x) & 0xffff0000u);
        a2 += u2f(((unsigned)v0.y) << 16); a3 += u2f(((unsigned)v0.y) & 0xffff0000u);
        a4 += u2f(((unsigned)v0.z) << 16); a5 += u2f(((unsigned)v0.z) & 0xffff0000u);
        a6 += u2f(((unsigned)v0.w) << 16); a7 += u2f(((unsigned)v0.w) & 0xffff0000u);
    }

    a0 += __shfl_xor(a0, 32, 64); a1 += __shfl_xor(a1, 32, 64);
    a2 += __shfl_xor(a2, 32, 64); a3 += __shfl_xor(a3, 32, 64);
    a4 += __shfl_xor(a4, 32, 64); a5 += __shfl_xor(a5, 32, 64);
    a6 += __shfl_xor(a6, 32, 64); a7 += __shfl_xor(a7, 32, 64);

    if (half == 0) {
        float sc = inv[node];
        int4 p;
        p.x = (int)((unsigned)f2bf(a0 * sc) | ((unsigned)f2bf(a1 * sc) << 16));
        p.y = (int)((unsigned)f2bf(a2 * sc) | ((unsigned)f2bf(a3 * sc) << 16));
        p.z = (int)((unsigned)f2bf(a4 * sc) | ((unsigned)f2bf(a5 * sc) << 16));
        p.w = (int)((unsigned)f2bf(a6 * sc) | ((unsigned)f2bf(a7 * sc) << 16));
        *reinterpret_cast<int4*>(agg + (size_t)node * HIDC + coff) = p;
    }
}

// ---------- layer-1 f32 SAGE GEMM (K=25) ----------
template <int K>
__global__ __launch_bounds__(256) void sage_gemm_f32(
    const float* __restrict__ agg, const float* __restrict__ h,
    const float* __restrict__ Wl, const float* __restrict__ Wr,
    const float* __restrict__ bias,
    unsigned short* __restrict__ out, int nrows) {
    constexpr int BM = 64, BN = 64, BK = 16;
    __shared__ float sA[BK][BM + 4];
    __shared__ float sB[BK][BN + 4];
    const int tid = threadIdx.x;
    const int tx = tid & 15, ty = tid >> 4;
    const int rowbase = blockIdx.x * BM;
    const int colbase = blockIdx.y * BN;
    float acc[4][4] = {};
    const int lrow = tid >> 2, lkq = (tid & 3) * 4;
    const int lkB = tid >> 4, lnB = (tid & 15) * 4;

    for (int pass = 0; pass < 2; ++pass) {
        const float* __restrict__ A = pass ? h : agg;
        const float* __restrict__ W = pass ? Wr : Wl;
        const int grow = rowbase + lrow;
        for (int kb = 0; kb < K; kb += BK) {
#pragma unroll
            for (int j = 0; j < 4; ++j) {
                int k = kb + lkq + j;
                float v = 0.0f;
                if (grow < nrows && k < K) v = A[(size_t)grow * K + k];
                sA[lkq + j][lrow] = v;
            }
#pragma unroll
            for (int j = 0; j < 4; ++j) {
                int k = kb + lkB;
                int n = colbase + lnB + j;
                sB[lkB][lnB + j] = (k < K) ? W[(size_t)k * HIDC + n] : 0.0f;
            }
            __syncthreads();
#pragma unroll
            for (int kk = 0; kk < BK; ++kk) {
                float a[4], b[4];
#pragma unroll
                for (int i = 0; i < 4; ++i) a[i] = sA[kk][ty * 4 + i];
#pragma unroll
                for (int j = 0; j < 4; ++j) b[j] = sB[kk][tx * 4 + j];
#pragma unroll
                for (int i = 0; i < 4; ++i)
#pragma unroll
                    for (int j = 0; j < 4; ++j) acc[i][j] += a[i] * b[j];
            }
            __syncthreads();
        }
    }
#pragma unroll
    for (int i = 0; i < 4; ++i) {
        int r = rowbase + ty * 4 + i;
        if (r >= nrows) continue;
#pragma unroll
        for (int j = 0; j < 4; ++j) {
            int c = colbase + tx * 4 + j;
            out[(size_t)r * HIDC + c] = f2bf(fmaxf(acc[i][j] + bias[c], 0.0f));
        }
    }
}

// ---------- MFMA bf16 SAGE GEMM: full-width block, B-in-LDS (swizzled) ----------
// out = relu(A0@B0 + A1@B1 + b). A: [M][256] bf16. BnT: [256 n][256 k] bf16.
// Block: 512 threads = 8 waves (2 wm x 4 wn), tile 128 rows x 256 cols.
// Full-width rows => whole 512B output rows written by one block (clean HBM writes).
// Per pass x half: stage B [256 cols][128 k] -> 64KB XOR-swizzled LDS (2 barriers),
// then 4 barrier-free k-steps with ds_read B + 2-deep global A prefetch.
__global__ __launch_bounds__(512, 4) void sage_gemm_mfma(
    const unsigned short* __restrict__ A0, const unsigned short* __restrict__ A1,
    const unsigned short* __restrict__ B0T, const unsigned short* __restrict__ B1T,
    const float* __restrict__ bias, unsigned short* __restrict__ out, int M) {
    constexpr int KD = 256;
    __shared__ unsigned short sB[256 * 128];  // 64KB
    const int rowbase = blockIdx.x * 128;
    const int tid = threadIdx.x;
    const int lane = tid & 63;
    const int wid = tid >> 6;      // 0..7
    const int wm = wid >> 2;       // 0..1
    const int wn = wid & 3;        // 0..3
    const int fr = lane & 15;
    const int kq8 = (lane >> 4) << 3;  // 0,8,16,24

    f32x4 acc[4][4] = {};
    const int arow0 = rowbase + wm * 64 + fr;

#pragma unroll
    for (int pass = 0; pass < 2; ++pass) {
        const unsigned short* __restrict__ A = pass ? A1 : A0;
        const unsigned short* __restrict__ BT = pass ? B1T : B0T;
#pragma unroll
        for (int half = 0; half < 2; ++half) {
            const int kbase = half * 128;
            // ---- stage B slice [256 cols][128 k] ----
            int4 gv[8];
#pragma unroll
            for (int c = 0; c < 8; ++c) {
                int chunk = (c << 9) + tid;  // 4096 chunks of 16B
                int r = chunk >> 4, k16 = chunk & 15;
                gv[c] = *reinterpret_cast<const int4*>(
                    BT + (size_t)r * KD + kbase + k16 * 8);
            }
            __syncthreads();  // prior half's frag reads complete
#pragma unroll
            for (int c = 0; c < 8; ++c) {
                int chunk = (c << 9) + tid;
                int r = chunk >> 4, k16 = chunk & 15;
                int byte = (r * 256 + k16 * 16) ^ ((r & 7) << 4);
                *reinterpret_cast<int4*>(reinterpret_cast<char*>(sB) + byte) = gv[c];
            }
            __syncthreads();
            // ---- 4 k-steps, no barriers; A prefetched 2 deep ----
            int4 ac[4], an[4];
#pragma unroll
            for (int i = 0; i < 4; ++i) {
                int r = arow0 + i * 16;
                ac[i] = (r < M) ? *reinterpret_cast<const int4*>(A + (size_t)r * KD + kbase + kq8)
                                : make_int4(0, 0, 0, 0);
                an[i] = (r < M) ? *reinterpret_cast<const int4*>(A + (size_t)r * KD + kbase + 32 + kq8)
                                : make_int4(0, 0, 0, 0);
            }
#pragma unroll
            for (int ks = 0; ks < 4; ++ks) {
                bf16x8 bfrag[4];
#pragma unroll
                for (int j = 0; j < 4; ++j) {
                    int row = wn * 64 + j * 16 + fr;
                    int byte = (row * 256 + ks * 64 + kq8 * 2) ^ ((row & 7) << 4);
                    bfrag[j] = *reinterpret_cast<const bf16x8*>(
                        reinterpret_cast<const char*>(sB) + byte);
                }
                int4 af[4];
                if (ks < 2) {
#pragma unroll
                    for (int i = 0; i < 4; ++i) {
                        int r = arow0 + i * 16;
                        af[i] = (r < M)
                                    ? *reinterpret_cast<const int4*>(
                                          A + (size_t)r * KD + kbase + (ks + 2) * 32 + kq8)
                                    : make_int4(0, 0, 0, 0);
                    }
                }
#pragma unroll
                for (int i = 0; i < 4; ++i)
#pragma unroll
                    for (int j = 0; j < 4; ++j)
                        acc[i][j] = __builtin_amdgcn_mfma_f32_16x16x32_bf16(
                            __builtin_bit_cast(bf16x8, ac[i]), bfrag[j], acc[i][j], 0, 0, 0);
#pragma unroll
                for (int i = 0; i < 4; ++i) { ac[i] = an[i]; an[i] = af[i]; }
            }
        }
    }

    // epilogue: C/D layout col=lane&15, row=4*(lane>>4)+r
    const int crow0 = (lane >> 4) << 2;
#pragma unroll
    for (int i = 0; i < 4; ++i) {
#pragma unroll
        for (int j = 0; j < 4; ++j) {
            int col = wn * 64 + j * 16 + fr;
            float bb = bias[col];
#pragma unroll
            for (int r = 0; r < 4; ++r) {
                int row = rowbase + wm * 64 + i * 16 + crow0 + r;
                if (row < M)
                    out[(size_t)row * HIDC + col] = f2bf(fmaxf(acc[i][j][r] + bb, 0.0f));
            }
        }
    }
}

// ---------- segment-max pool: 8-way parallel per graph, atomicMax (values >= 0) ----------
__global__ void pool_max(const unsigned short* __restrict__ h, const int* __restrict__ gstart,
                         const int* __restrict__ gend, float* __restrict__ xc, int col_off) {
    int g = blockIdx.x;
    int chunk = blockIdx.y;  // 0..7
    int c = threadIdx.x;
    int s = gstart[g], e = gend[g];
    int len = e - s;
    if (len <= 0) return;
    int per = (len + 7) >> 3;
    int cs = s + chunk * per;
    int ce = min(cs + per, e);
    if (cs >= ce) return;
    float m = 0.0f;  // relu outputs >= 0
    for (int i = cs; i < ce; ++i) m = fmaxf(m, bf2f(h[(size_t)i * HIDC + c]));
    // xc zero-filled; all values >= 0 so int compare == float compare
    atomicMax(reinterpret_cast<int*>(&xc[(size_t)g * (3 * HIDC) + col_off + c]),
              __float_as_int(m));
}

// ---------- head MLPs ----------
__global__ void mlp1(const float* __restrict__ xc, const float* __restrict__ W,
                     const float* __restrict__ b, float* __restrict__ hmid) {
    __shared__ float row[3 * HIDC];
    int g = blockIdx.x;
    for (int i = threadIdx.x; i < 3 * HIDC; i += 256) row[i] = xc[(size_t)g * (3 * HIDC) + i];
    __syncthreads();
    float acc = b[threadIdx.x];
    for (int k = 0; k < 3 * HIDC; ++k) acc += row[k] * W[(size_t)k * HIDC + threadIdx.x];
    hmid[(size_t)g * HIDC + threadIdx.x] = fmaxf(acc, 0.0f);
}

__global__ void mlp2(const float* __restrict__ hmid, const float* __restrict__ W,
                     const float* __restrict__ b, float* __restrict__ out) {
    __shared__ float row[HIDC];
    int g = blockIdx.x;
    for (int i = threadIdx.x; i < HIDC; i += 128) row[i] = hmid[(size_t)g * HIDC + i];
    __syncthreads();
    float acc = b[threadIdx.x];
    for (int k = 0; k < HIDC; ++k) acc += row[k] * W[(size_t)k * OUT_DIMC + threadIdx.x];
    out[(size_t)g * OUT_DIMC + threadIdx.x] = acc;
}

static inline char* align_up(char* p, size_t a) {
    return (char*)(((uintptr_t)p + a - 1) & ~(uintptr_t)(a - 1));
}

extern "C" void kernel_launch(void* const* d_in, const int* in_sizes, int n_in,
                              void* d_out, int out_size, void* d_ws, size_t ws_size,
                              hipStream_t stream) {
    const float* x = (const float*)d_in[0];
    const int* edge_index = (const int*)d_in[1];
    const int* batch = (const int*)d_in[2];
    const float* W1l = (const float*)d_in[3];
    const float* W1r = (const float*)d_in[4];
    const float* b1 = (const float*)d_in[5];
    const float* W2l = (const float*)d_in[6];
    const float* W2r = (const float*)d_in[7];
    const float* b2 = (const float*)d_in[8];
    const float* W3l = (const float*)d_in[9];
    const float* W3r = (const float*)d_in[10];
    const float* b3 = (const float*)d_in[11];
    const float* Wlin1 = (const float*)d_in[12];
    const float* blin1 = (const float*)d_in[13];
    const float* Wlin2 = (const float*)d_in[14];
    const float* blin2 = (const float*)d_in[15];
    float* out = (float*)d_out;

    const int N = N_NODESC, E = N_EDGESC;
    const int* src = edge_index;
    const int* dst = edge_index + E;

    // ---- workspace carve-up ----
    char* w0 = (char*)d_ws;
    char* w = w0;
    int* cnt = (int*)w;        w = align_up(w + (size_t)N * 4, 256);
    float* invc = (float*)w;   w = align_up(w + (size_t)N * 4, 256);
    int* row_ofs = (int*)w;    w = align_up(w + (size_t)(N + 1) * 4, 256);
    int* bsum = (int*)w;       w = align_up(w + (size_t)SCAN_NBLK * 4, 256);
    int* csr = (int*)w;        w = align_up(w + (size_t)E * 4, 256);
    int* gstart = (int*)w;     w = align_up(w + (size_t)N_GRAPHSC * 4, 256);
    int* gend = (int*)w;       w = align_up(w + (size_t)N_GRAPHSC * 4, 256);
    float* xc = (float*)w;     w = align_up(w + (size_t)N_GRAPHSC * 3 * HIDC * 4, 256);
    float* hmid = (float*)w;   w = align_up(w + (size_t)N_GRAPHSC * HIDC * 4, 256);
    unsigned short* W2lT = (unsigned short*)w; w = align_up(w + (size_t)HIDC * HIDC * 2, 256);
    unsigned short* W2rT = (unsigned short*)w; w = align_up(w + (size_t)HIDC * HIDC * 2, 256);
    unsigned short* W3lT = (unsigned short*)w; w = align_up(w + (size_t)HIDC * HIDC * 2, 256);
    unsigned short* W3rT = (unsigned short*)w; w = align_up(w + (size_t)HIDC * HIDC * 2, 256);
    char* aggU = w;            w = align_up(w + (size_t)N * HIDC * 2, 256);
    unsigned short* h1 = (unsigned short*)w;  w = align_up(w + (size_t)N * HIDC * 2, 256);
    unsigned short* h2 = (unsigned short*)w;  w = align_up(w + (size_t)N * HIDC * 2, 256);
    size_t required = (size_t)(w - w0);
    if (ws_size < required) return;

    float* agg25 = (float*)aggU;
    unsigned short* aggH = (unsigned short*)aggU;

    const int nbN = (N + 255) / 256;
    const int nbE = (E + 255) / 256;
    const dim3 gemm_grid_f32((N + 63) / 64, HIDC / 64);
    const dim3 tgrid(16, 16);
    const dim3 pgrid(N_GRAPHSC, 8);

    // weight transposes
    wtransT<<<tgrid, 256, 0, stream>>>(W2l, W2lT);
    wtransT<<<tgrid, 256, 0, stream>>>(W2r, W2rT);
    wtransT<<<tgrid, 256, 0, stream>>>(W3l, W3lT);
    wtransT<<<tgrid, 256, 0, stream>>>(W3r, W3rT);

    // degrees + inv
    fill_u32<<<nbN, 256, 0, stream>>>((unsigned*)cnt, 0u, N);
    deg_kernel<<<nbE, 256, 0, stream>>>(dst, cnt, E);
    inv_kernel<<<nbN, 256, 0, stream>>>(cnt, invc, N);
    // CSR offsets: hierarchical scan
    scan_partial<<<SCAN_NBLK, SCAN_BLK, 0, stream>>>(cnt, row_ofs, bsum);
    scan_bsums<<<1, 128, 0, stream>>>(bsum);
    scan_add<<<SCAN_NBLK, SCAN_BLK, 0, stream>>>(row_ofs, bsum);
    fill_u32<<<nbN, 256, 0, stream>>>((unsigned*)cnt, 0u, N);
    csr_fill<<<nbE, 256, 0, stream>>>(src, dst, row_ofs, cnt, csr, E);
    // graph ranges + zero xc (pool uses atomicMax over non-negative floats)
    fill_u32<<<1, 256, 0, stream>>>((unsigned*)gstart, (unsigned)N, N_GRAPHSC);
    fill_u32<<<1, 256, 0, stream>>>((unsigned*)gend, 0u, N_GRAPHSC);
    ranges_bounds<<<nbN, 256, 0, stream>>>(batch, gstart, gend, N);
    fill_u32<<<(N_GRAPHSC * 3 * HIDC + 255) / 256, 256, 0, stream>>>((unsigned*)xc, 0u,
                                                                     N_GRAPHSC * 3 * HIDC);

    // ---- layer 1 (K=25, f32) ----
    gather25<<<(N * 32 + 255) / 256, 256, 0, stream>>>(x, row_ofs, csr, invc, agg25);
    sage_gemm_f32<IN_DIMC><<<gemm_grid_f32, 256, 0, stream>>>(agg25, x, W1l, W1r, b1, h1, N);
    pool_max<<<pgrid, 256, 0, stream>>>(h1, gstart, gend, xc, 0);

    // ---- layer 2 (MFMA, full-width B-in-LDS) ----
    gather256<<<(N * 64 + 255) / 256, 256, 0, stream>>>(h1, row_ofs, csr, invc, aggH);
    sage_gemm_mfma<<<NRB, 512, 0, stream>>>(aggH, h1, W2lT, W2rT, b2, h2, N);
    pool_max<<<pgrid, 256, 0, stream>>>(h2, gstart, gend, xc, HIDC);

    // ---- layer 3 (MFMA, full-width B-in-LDS) ----
    gather256<<<(N * 64 + 255) / 256, 256, 0, stream>>>(h2, row_ofs, csr, invc, aggH);
    sage_gemm_mfma<<<NRB, 512, 0, stream>>>(aggH, h2, W3lT, W3rT, b3, h1, N);
    pool_max<<<pgrid, 256, 0, stream>>>(h1, gstart, gend, xc, 2 * HIDC);

    // ---- head ----
    mlp1<<<N_GRAPHSC, 256, 0, stream>>>(xc, Wlin1, blin1, hmid);
    mlp2<<<N_GRAPHSC, 128, 0, stream>>>(hmid, Wlin2, blin2, out);
}

// Round 10
// 915.878 us; speedup vs baseline: 1.4190x; 1.4190x over previous
//
#include <hip/hip_runtime.h>
#include <hip/hip_bf16.h>

#define N_NODESC 100000
#define N_EDGESC 1600000
#define N_GRAPHSC 200
#define IN_DIMC 25
#define HIDC 256
#define OUT_DIMC 128
#define SCAN_BLK 1024
#define SCAN_NBLK ((N_NODESC + SCAN_BLK - 1) / SCAN_BLK)
#define NRB ((N_NODESC + 127) / 128)  // 782 row-blocks

typedef __attribute__((ext_vector_type(8))) short bf16x8;
typedef __attribute__((ext_vector_type(4))) float f32x4;

// ---------- bf16 helpers (raw ushort storage) ----------
__device__ inline float bf2f(unsigned short u) {
    union { float f; unsigned u32; } c;
    c.u32 = ((unsigned)u) << 16;
    return c.f;
}
__device__ inline unsigned short f2bf(float f) {
    union { float f; unsigned u; } c;
    c.f = f;
    unsigned r = (c.u + 0x7FFFu + ((c.u >> 16) & 1u)) >> 16;  // RNE
    return (unsigned short)r;
}
__device__ inline float u2f(unsigned u) {
    union { unsigned u; float f; } c;
    c.u = u;
    return c.f;
}

// ---------- utility fills ----------
__global__ void fill_u32(unsigned* __restrict__ p, unsigned v, int n) {
    int i = blockIdx.x * 256 + threadIdx.x;
    if (i < n) p[i] = v;
}

// ---------- degree / inv ----------
__global__ void deg_kernel(const int* __restrict__ dst, int* __restrict__ cnt, int E) {
    int i = blockIdx.x * 256 + threadIdx.x;
    if (i < E) atomicAdd(&cnt[dst[i]], 1);
}
__global__ void inv_kernel(const int* __restrict__ cnt, float* __restrict__ inv, int n) {
    int i = blockIdx.x * 256 + threadIdx.x;
    if (i < n) inv[i] = 1.0f / (float)max(cnt[i], 1);
}

// ---------- hierarchical exclusive scan over cnt[N] -> ofs[N+1] ----------
__global__ __launch_bounds__(SCAN_BLK) void scan_partial(const int* __restrict__ cnt,
                                                         int* __restrict__ ofs,
                                                         int* __restrict__ bsum) {
    __shared__ int sm[SCAN_BLK];
    int i = blockIdx.x * SCAN_BLK + threadIdx.x;
    int v = (i < N_NODESC) ? cnt[i] : 0;
    sm[threadIdx.x] = v;
    __syncthreads();
    for (int off = 1; off < SCAN_BLK; off <<= 1) {
        int t = (threadIdx.x >= off) ? sm[threadIdx.x - off] : 0;
        __syncthreads();
        sm[threadIdx.x] += t;
        __syncthreads();
    }
    if (i < N_NODESC) ofs[i] = sm[threadIdx.x] - v;  // exclusive within block
    if (threadIdx.x == SCAN_BLK - 1) bsum[blockIdx.x] = sm[SCAN_BLK - 1];
}

__global__ __launch_bounds__(128) void scan_bsums(int* __restrict__ bsum) {
    __shared__ int sm[SCAN_NBLK];
    if (threadIdx.x == 0) {
        int run = 0;
        for (int b = 0; b < SCAN_NBLK; ++b) {
            int t = bsum[b];
            sm[b] = run;
            run += t;
        }
        for (int b = 0; b < SCAN_NBLK; ++b) bsum[b] = sm[b];
    }
}

__global__ __launch_bounds__(SCAN_BLK) void scan_add(int* __restrict__ ofs,
                                                     const int* __restrict__ bsum) {
    int i = blockIdx.x * SCAN_BLK + threadIdx.x;
    if (i < N_NODESC) ofs[i] += bsum[blockIdx.x];
    if (i == 0) ofs[N_NODESC] = N_EDGESC;
}

// ---------- CSR fill ----------
__global__ void csr_fill(const int* __restrict__ src, const int* __restrict__ dst,
                         const int* __restrict__ ofs, int* __restrict__ cursor,
                         int* __restrict__ csr, int E) {
    int e = blockIdx.x * 256 + threadIdx.x;
    if (e < E) {
        int d = dst[e];
        int pos = atomicAdd(&cursor[d], 1);
        csr[ofs[d] + pos] = src[e];
    }
}

// ---------- graph ranges: boundary scan (batch sorted; no atomics) ----------
__global__ void ranges_bounds(const int* __restrict__ batch, int* __restrict__ gstart,
                              int* __restrict__ gend, int n) {
    int i = blockIdx.x * 256 + threadIdx.x;
    if (i >= n) return;
    int g = batch[i];
    if (i == 0 || batch[i - 1] != g) gstart[g] = i;
    if (i == n - 1 || batch[i + 1] != g) gend[g] = i + 1;
}

// ---------- weight transpose f32[256][256] -> bf16 WT[n][k] ----------
__global__ void wtransT(const float* __restrict__ W, unsigned short* __restrict__ WT) {
    __shared__ float t[16][17];
    int bx = blockIdx.x, by = blockIdx.y;
    int tx = threadIdx.x & 15, ty = threadIdx.x >> 4;
    t[ty][tx] = W[(by * 16 + ty) * HIDC + bx * 16 + tx];
    __syncthreads();
    WT[(size_t)(bx * 16 + ty) * HIDC + by * 16 + tx] = f2bf(t[tx][ty]);
}

// ---------- layer-1 mean gather (f32, 25 channels) ----------
__global__ void gather25(const float* __restrict__ x, const int* __restrict__ ofs,
                         const int* __restrict__ csr, const float* __restrict__ inv,
                         float* __restrict__ agg) {
    int idx = blockIdx.x * 256 + threadIdx.x;
    int node = idx >> 5, c = idx & 31;
    if (node >= N_NODESC || c >= IN_DIMC) return;
    float acc = 0.0f;
    int s = ofs[node], e = ofs[node + 1];
    for (int j = s; j < e; ++j) acc += x[(size_t)csr[j] * IN_DIMC + c];
    agg[(size_t)node * IN_DIMC + c] = acc * inv[node];
}

// ---------- hidden mean gather: one wave/node, half-wave/edge, 16B lanes ----------
__global__ void gather256(const unsigned short* __restrict__ h, const int* __restrict__ ofs,
                          const int* __restrict__ csr, const float* __restrict__ inv,
                          unsigned short* __restrict__ agg) {
    long long gtid = (long long)blockIdx.x * 256 + threadIdx.x;
    int node = (int)(gtid >> 6);
    if (node >= N_NODESC) return;
    const int lane = threadIdx.x & 63;
    const int half = lane >> 5;
    const int l = lane & 31;
    const int s = ofs[node], e = ofs[node + 1];

    float a0 = 0, a1 = 0, a2 = 0, a3 = 0, a4 = 0, a5 = 0, a6 = 0, a7 = 0;
    const size_t coff = (size_t)l * 8;

    int j = s + half;
    for (; j + 2 < e; j += 4) {
        int sn0 = csr[j];
        int sn1 = csr[j + 2];
        int4 v0 = *reinterpret_cast<const int4*>(h + (size_t)sn0 * HIDC + coff);
        int4 v1 = *reinterpret_cast<const int4*>(h + (size_t)sn1 * HIDC + coff);
        a0 += u2f(((unsigned)v0.x) << 16); a1 += u2f(((unsigned)v0.x) & 0xffff0000u);
        a2 += u2f(((unsigned)v0.y) << 16); a3 += u2f(((unsigned)v0.y) & 0xffff0000u);
        a4 += u2f(((unsigned)v0.z) << 16); a5 += u2f(((unsigned)v0.z) & 0xffff0000u);
        a6 += u2f(((unsigned)v0.w) << 16); a7 += u2f(((unsigned)v0.w) & 0xffff0000u);
        a0 += u2f(((unsigned)v1.x) << 16); a1 += u2f(((unsigned)v1.x) & 0xffff0000u);
        a2 += u2f(((unsigned)v1.y) << 16); a3 += u2f(((unsigned)v1.y) & 0xffff0000u);
        a4 += u2f(((unsigned)v1.z) << 16); a5 += u2f(((unsigned)v1.z) & 0xffff0000u);
        a6 += u2f(((unsigned)v1.w) << 16); a7 += u2f(((unsigned)v1.w) & 0xffff0000u);
    }
    if (j < e) {
        int sn0 = csr[j];
        int4 v0 = *reinterpret_cast<const int4*>(h + (size_t)sn0 * HIDC + coff);
        a0 += u2f(((unsigned)v0.x) << 16); a1 += u2f(((unsigned)v0.x) & 0xffff0000u);
        a2 += u2f(((unsigned)v0.y) << 16); a3 += u2f(((unsigned)v0.y) & 0xffff0000u);
        a4 += u2f(((unsigned)v0.z) << 16); a5 += u2f(((unsigned)v0.z) & 0xffff0000u);
        a6 += u2f(((unsigned)v0.w) << 16); a7 += u2f(((unsigned)v0.w) & 0xffff0000u);
    }

    a0 += __shfl_xor(a0, 32, 64); a1 += __shfl_xor(a1, 32, 64);
    a2 += __shfl_xor(a2, 32, 64); a3 += __shfl_xor(a3, 32, 64);
    a4 += __shfl_xor(a4, 32, 64); a5 += __shfl_xor(a5, 32, 64);
    a6 += __shfl_xor(a6, 32, 64); a7 += __shfl_xor(a7, 32, 64);

    if (half == 0) {
        float sc = inv[node];
        int4 p;
        p.x = (int)((unsigned)f2bf(a0 * sc) | ((unsigned)f2bf(a1 * sc) << 16));
        p.y = (int)((unsigned)f2bf(a2 * sc) | ((unsigned)f2bf(a3 * sc) << 16));
        p.z = (int)((unsigned)f2bf(a4 * sc) | ((unsigned)f2bf(a5 * sc) << 16));
        p.w = (int)((unsigned)f2bf(a6 * sc) | ((unsigned)f2bf(a7 * sc) << 16));
        *reinterpret_cast<int4*>(agg + (size_t)node * HIDC + coff) = p;
    }
}

// ---------- layer-1 f32 SAGE GEMM (K=25) ----------
template <int K>
__global__ __launch_bounds__(256) void sage_gemm_f32(
    const float* __restrict__ agg, const float* __restrict__ h,
    const float* __restrict__ Wl, const float* __restrict__ Wr,
    const float* __restrict__ bias,
    unsigned short* __restrict__ out, int nrows) {
    constexpr int BM = 64, BN = 64, BK = 16;
    __shared__ float sA[BK][BM + 4];
    __shared__ float sB[BK][BN + 4];
    const int tid = threadIdx.x;
    const int tx = tid & 15, ty = tid >> 4;
    const int rowbase = blockIdx.x * BM;
    const int colbase = blockIdx.y * BN;
    float acc[4][4] = {};
    const int lrow = tid >> 2, lkq = (tid & 3) * 4;
    const int lkB = tid >> 4, lnB = (tid & 15) * 4;

    for (int pass = 0; pass < 2; ++pass) {
        const float* __restrict__ A = pass ? h : agg;
        const float* __restrict__ W = pass ? Wr : Wl;
        const int grow = rowbase + lrow;
        for (int kb = 0; kb < K; kb += BK) {
#pragma unroll
            for (int j = 0; j < 4; ++j) {
                int k = kb + lkq + j;
                float v = 0.0f;
                if (grow < nrows && k < K) v = A[(size_t)grow * K + k];
                sA[lkq + j][lrow] = v;
            }
#pragma unroll
            for (int j = 0; j < 4; ++j) {
                int k = kb + lkB;
                int n = colbase + lnB + j;
                sB[lkB][lnB + j] = (k < K) ? W[(size_t)k * HIDC + n] : 0.0f;
            }
            __syncthreads();
#pragma unroll
            for (int kk = 0; kk < BK; ++kk) {
                float a[4], b[4];
#pragma unroll
                for (int i = 0; i < 4; ++i) a[i] = sA[kk][ty * 4 + i];
#pragma unroll
                for (int j = 0; j < 4; ++j) b[j] = sB[kk][tx * 4 + j];
#pragma unroll
                for (int i = 0; i < 4; ++i)
#pragma unroll
                    for (int j = 0; j < 4; ++j) acc[i][j] += a[i] * b[j];
            }
            __syncthreads();
        }
    }
#pragma unroll
    for (int i = 0; i < 4; ++i) {
        int r = rowbase + ty * 4 + i;
        if (r >= nrows) continue;
#pragma unroll
        for (int j = 0; j < 4; ++j) {
            int c = colbase + tx * 4 + j;
            out[(size_t)r * HIDC + c] = f2bf(fmaxf(acc[i][j] + bias[c], 0.0f));
        }
    }
}

// ---------- MFMA bf16 SAGE GEMM: full-width tile, A+B in padded LDS (round-6 loop) ----------
// out = relu(A0@B0 + A1@B1 + b). A: [M][256] bf16. BnT: [256 n][256 k] bf16.
// 512 threads = 8 waves (2 wm x 4 wn); tile 128 rows x 256 cols (full width =>
// whole 512B output rows per block, no partial-row write amplification).
// Per BK=32 step: stage A(128x32, 1 int4/thread) + B(256x32, 2 int4/thread)
// into padded LDS (LDA=40), 2 barriers, then 16 MFMAs per wave.
__global__ __launch_bounds__(512) void sage_gemm_mfma(
    const unsigned short* __restrict__ A0, const unsigned short* __restrict__ A1,
    const unsigned short* __restrict__ B0T, const unsigned short* __restrict__ B1T,
    const float* __restrict__ bias, unsigned short* __restrict__ out, int M) {
    constexpr int KD = 256, LDA = 40;
    __shared__ unsigned short sA[128 * LDA];  // 10 KB
    __shared__ unsigned short sB[256 * LDA];  // 20 KB
    const int rowbase = blockIdx.x * 128;
    const int tid = threadIdx.x;
    const int lane = tid & 63;
    const int wid = tid >> 6;      // 0..7
    const int wm = wid >> 2;       // 0..1
    const int wn = wid & 3;        // 0..3
    const int fr = lane & 15;
    const int kq8 = (lane >> 4) << 3;  // 0,8,16,24

    f32x4 acc[4][4] = {};
    const int ar = tid >> 2, akq = (tid & 3) << 3;  // A loader: row 0..127, k-quad

#pragma unroll
    for (int pass = 0; pass < 2; ++pass) {
        const unsigned short* __restrict__ A = pass ? A1 : A0;
        const unsigned short* __restrict__ BT = pass ? B1T : B0T;
        for (int kb = 0; kb < KD; kb += 32) {
            // stage to regs
            int4 av;
            {
                int gr = rowbase + ar;
                av = (gr < M) ? *reinterpret_cast<const int4*>(A + (size_t)gr * KD + kb + akq)
                              : make_int4(0, 0, 0, 0);
            }
            int4 bv[2];
#pragma unroll
            for (int c = 0; c < 2; ++c) {
                int chunk = (c << 9) + tid;  // 1024 chunks of 16B
                int r = chunk >> 2, kq = (chunk & 3) << 3;
                bv[c] = *reinterpret_cast<const int4*>(BT + (size_t)r * KD + kb + kq);
            }
            __syncthreads();  // prior iter's frag reads done
            *reinterpret_cast<int4*>(sA + ar * LDA + akq) = av;
#pragma unroll
            for (int c = 0; c < 2; ++c) {
                int chunk = (c << 9) + tid;
                int r = chunk >> 2, kq = (chunk & 3) << 3;
                *reinterpret_cast<int4*>(sB + r * LDA + kq) = bv[c];
            }
            __syncthreads();
            // frags + MFMA
            bf16x8 af[4], bfr[4];
#pragma unroll
            for (int t = 0; t < 4; ++t) {
                af[t] = *reinterpret_cast<const bf16x8*>(sA + (wm * 64 + t * 16 + fr) * LDA + kq8);
                bfr[t] = *reinterpret_cast<const bf16x8*>(sB + (wn * 64 + t * 16 + fr) * LDA + kq8);
            }
#pragma unroll
            for (int i = 0; i < 4; ++i)
#pragma unroll
                for (int j = 0; j < 4; ++j)
                    acc[i][j] = __builtin_amdgcn_mfma_f32_16x16x32_bf16(af[i], bfr[j], acc[i][j], 0, 0, 0);
        }
    }

    // epilogue: C/D layout col=lane&15, row=4*(lane>>4)+r
    const int crow0 = (lane >> 4) << 2;
#pragma unroll
    for (int i = 0; i < 4; ++i) {
#pragma unroll
        for (int j = 0; j < 4; ++j) {
            int col = wn * 64 + j * 16 + fr;
            float bb = bias[col];
#pragma unroll
            for (int r = 0; r < 4; ++r) {
                int row = rowbase + wm * 64 + i * 16 + crow0 + r;
                if (row < M)
                    out[(size_t)row * HIDC + col] = f2bf(fmaxf(acc[i][j][r] + bb, 0.0f));
            }
        }
    }
}

// ---------- segment-max pool: 8-way parallel per graph, atomicMax (values >= 0) ----------
__global__ void pool_max(const unsigned short* __restrict__ h, const int* __restrict__ gstart,
                         const int* __restrict__ gend, float* __restrict__ xc, int col_off) {
    int g = blockIdx.x;
    int chunk = blockIdx.y;  // 0..7
    int c = threadIdx.x;
    int s = gstart[g], e = gend[g];
    int len = e - s;
    if (len <= 0) return;
    int per = (len + 7) >> 3;
    int cs = s + chunk * per;
    int ce = min(cs + per, e);
    if (cs >= ce) return;
    float m = 0.0f;  // relu outputs >= 0
    for (int i = cs; i < ce; ++i) m = fmaxf(m, bf2f(h[(size_t)i * HIDC + c]));
    atomicMax(reinterpret_cast<int*>(&xc[(size_t)g * (3 * HIDC) + col_off + c]),
              __float_as_int(m));
}

// ---------- head MLPs ----------
__global__ void mlp1(const float* __restrict__ xc, const float* __restrict__ W,
                     const float* __restrict__ b, float* __restrict__ hmid) {
    __shared__ float row[3 * HIDC];
    int g = blockIdx.x;
    for (int i = threadIdx.x; i < 3 * HIDC; i += 256) row[i] = xc[(size_t)g * (3 * HIDC) + i];
    __syncthreads();
    float acc = b[threadIdx.x];
    for (int k = 0; k < 3 * HIDC; ++k) acc += row[k] * W[(size_t)k * HIDC + threadIdx.x];
    hmid[(size_t)g * HIDC + threadIdx.x] = fmaxf(acc, 0.0f);
}

__global__ void mlp2(const float* __restrict__ hmid, const float* __restrict__ W,
                     const float* __restrict__ b, float* __restrict__ out) {
    __shared__ float row[HIDC];
    int g = blockIdx.x;
    for (int i = threadIdx.x; i < HIDC; i += 128) row[i] = hmid[(size_t)g * HIDC + i];
    __syncthreads();
    float acc = b[threadIdx.x];
    for (int k = 0; k < HIDC; ++k) acc += row[k] * W[(size_t)k * OUT_DIMC + threadIdx.x];
    out[(size_t)g * OUT_DIMC + threadIdx.x] = acc;
}

static inline char* align_up(char* p, size_t a) {
    return (char*)(((uintptr_t)p + a - 1) & ~(uintptr_t)(a - 1));
}

extern "C" void kernel_launch(void* const* d_in, const int* in_sizes, int n_in,
                              void* d_out, int out_size, void* d_ws, size_t ws_size,
                              hipStream_t stream) {
    const float* x = (const float*)d_in[0];
    const int* edge_index = (const int*)d_in[1];
    const int* batch = (const int*)d_in[2];
    const float* W1l = (const float*)d_in[3];
    const float* W1r = (const float*)d_in[4];
    const float* b1 = (const float*)d_in[5];
    const float* W2l = (const float*)d_in[6];
    const float* W2r = (const float*)d_in[7];
    const float* b2 = (const float*)d_in[8];
    const float* W3l = (const float*)d_in[9];
    const float* W3r = (const float*)d_in[10];
    const float* b3 = (const float*)d_in[11];
    const float* Wlin1 = (const float*)d_in[12];
    const float* blin1 = (const float*)d_in[13];
    const float* Wlin2 = (const float*)d_in[14];
    const float* blin2 = (const float*)d_in[15];
    float* out = (float*)d_out;

    const int N = N_NODESC, E = N_EDGESC;
    const int* src = edge_index;
    const int* dst = edge_index + E;

    // ---- workspace carve-up ----
    char* w0 = (char*)d_ws;
    char* w = w0;
    int* cnt = (int*)w;        w = align_up(w + (size_t)N * 4, 256);
    float* invc = (float*)w;   w = align_up(w + (size_t)N * 4, 256);
    int* row_ofs = (int*)w;    w = align_up(w + (size_t)(N + 1) * 4, 256);
    int* bsum = (int*)w;       w = align_up(w + (size_t)SCAN_NBLK * 4, 256);
    int* csr = (int*)w;        w = align_up(w + (size_t)E * 4, 256);
    int* gstart = (int*)w;     w = align_up(w + (size_t)N_GRAPHSC * 4, 256);
    int* gend = (int*)w;       w = align_up(w + (size_t)N_GRAPHSC * 4, 256);
    float* xc = (float*)w;     w = align_up(w + (size_t)N_GRAPHSC * 3 * HIDC * 4, 256);
    float* hmid = (float*)w;   w = align_up(w + (size_t)N_GRAPHSC * HIDC * 4, 256);
    unsigned short* W2lT = (unsigned short*)w; w = align_up(w + (size_t)HIDC * HIDC * 2, 256);
    unsigned short* W2rT = (unsigned short*)w; w = align_up(w + (size_t)HIDC * HIDC * 2, 256);
    unsigned short* W3lT = (unsigned short*)w; w = align_up(w + (size_t)HIDC * HIDC * 2, 256);
    unsigned short* W3rT = (unsigned short*)w; w = align_up(w + (size_t)HIDC * HIDC * 2, 256);
    char* aggU = w;            w = align_up(w + (size_t)N * HIDC * 2, 256);
    unsigned short* h1 = (unsigned short*)w;  w = align_up(w + (size_t)N * HIDC * 2, 256);
    unsigned short* h2 = (unsigned short*)w;  w = align_up(w + (size_t)N * HIDC * 2, 256);
    size_t required = (size_t)(w - w0);
    if (ws_size < required) return;

    float* agg25 = (float*)aggU;
    unsigned short* aggH = (unsigned short*)aggU;

    const int nbN = (N + 255) / 256;
    const int nbE = (E + 255) / 256;
    const dim3 gemm_grid_f32((N + 63) / 64, HIDC / 64);
    const dim3 tgrid(16, 16);
    const dim3 pgrid(N_GRAPHSC, 8);

    // weight transposes
    wtransT<<<tgrid, 256, 0, stream>>>(W2l, W2lT);
    wtransT<<<tgrid, 256, 0, stream>>>(W2r, W2rT);
    wtransT<<<tgrid, 256, 0, stream>>>(W3l, W3lT);
    wtransT<<<tgrid, 256, 0, stream>>>(W3r, W3rT);

    // degrees + inv
    fill_u32<<<nbN, 256, 0, stream>>>((unsigned*)cnt, 0u, N);
    deg_kernel<<<nbE, 256, 0, stream>>>(dst, cnt, E);
    inv_kernel<<<nbN, 256, 0, stream>>>(cnt, invc, N);
    // CSR offsets: hierarchical scan
    scan_partial<<<SCAN_NBLK, SCAN_BLK, 0, stream>>>(cnt, row_ofs, bsum);
    scan_bsums<<<1, 128, 0, stream>>>(bsum);
    scan_add<<<SCAN_NBLK, SCAN_BLK, 0, stream>>>(row_ofs, bsum);
    fill_u32<<<nbN, 256, 0, stream>>>((unsigned*)cnt, 0u, N);
    csr_fill<<<nbE, 256, 0, stream>>>(src, dst, row_ofs, cnt, csr, E);
    // graph ranges + zero xc (pool uses atomicMax over non-negative floats)
    fill_u32<<<1, 256, 0, stream>>>((unsigned*)gstart, (unsigned)N, N_GRAPHSC);
    fill_u32<<<1, 256, 0, stream>>>((unsigned*)gend, 0u, N_GRAPHSC);
    ranges_bounds<<<nbN, 256, 0, stream>>>(batch, gstart, gend, N);
    fill_u32<<<(N_GRAPHSC * 3 * HIDC + 255) / 256, 256, 0, stream>>>((unsigned*)xc, 0u,
                                                                     N_GRAPHSC * 3 * HIDC);

    // ---- layer 1 (K=25, f32) ----
    gather25<<<(N * 32 + 255) / 256, 256, 0, stream>>>(x, row_ofs, csr, invc, agg25);
    sage_gemm_f32<IN_DIMC><<<gemm_grid_f32, 256, 0, stream>>>(agg25, x, W1l, W1r, b1, h1, N);
    pool_max<<<pgrid, 256, 0, stream>>>(h1, gstart, gend, xc, 0);

    // ---- layer 2 (MFMA, full-width, A+B in LDS) ----
    gather256<<<(N * 64 + 255) / 256, 256, 0, stream>>>(h1, row_ofs, csr, invc, aggH);
    sage_gemm_mfma<<<NRB, 512, 0, stream>>>(aggH, h1, W2lT, W2rT, b2, h2, N);
    pool_max<<<pgrid, 256, 0, stream>>>(h2, gstart, gend, xc, HIDC);

    // ---- layer 3 (MFMA, full-width, A+B in LDS) ----
    gather256<<<(N * 64 + 255) / 256, 256, 0, stream>>>(h2, row_ofs, csr, invc, aggH);
    sage_gemm_mfma<<<NRB, 512, 0, stream>>>(aggH, h2, W3lT, W3rT, b3, h1, N);
    pool_max<<<pgrid, 256, 0, stream>>>(h1, gstart, gend, xc, 2 * HIDC);

    // ---- head ----
    mlp1<<<N_GRAPHSC, 256, 0, stream>>>(xc, Wlin1, blin1, hmid);
    mlp2<<<N_GRAPHSC, 128, 0, stream>>>(hmid, Wlin2, blin2, out);
}

// Round 11
// 777.132 us; speedup vs baseline: 1.6723x; 1.1785x over previous
//
#include <hip/hip_runtime.h>
#include <hip/hip_bf16.h>

#define N_NODESC 100000
#define N_EDGESC 1600000
#define N_GRAPHSC 200
#define IN_DIMC 25
#define HIDC 256
#define OUT_DIMC 128
#define SCAN_BLK 1024
#define SCAN_NBLK ((N_NODESC + SCAN_BLK - 1) / SCAN_BLK)
#define NRB64 ((N_NODESC + 63) / 64)  // 1563 row-blocks

typedef __attribute__((ext_vector_type(8))) short bf16x8;
typedef __attribute__((ext_vector_type(4))) float f32x4;

// ---------- bf16 helpers (raw ushort storage) ----------
__device__ inline float bf2f(unsigned short u) {
    union { float f; unsigned u32; } c;
    c.u32 = ((unsigned)u) << 16;
    return c.f;
}
__device__ inline unsigned short f2bf(float f) {
    union { float f; unsigned u; } c;
    c.f = f;
    unsigned r = (c.u + 0x7FFFu + ((c.u >> 16) & 1u)) >> 16;  // RNE
    return (unsigned short)r;
}
__device__ inline float u2f(unsigned u) {
    union { unsigned u; float f; } c;
    c.u = u;
    return c.f;
}

// ---------- utility fills ----------
__global__ void fill_u32(unsigned* __restrict__ p, unsigned v, int n) {
    int i = blockIdx.x * 256 + threadIdx.x;
    if (i < n) p[i] = v;
}

// ---------- degree / inv ----------
__global__ void deg_kernel(const int* __restrict__ dst, int* __restrict__ cnt, int E) {
    int i = blockIdx.x * 256 + threadIdx.x;
    if (i < E) atomicAdd(&cnt[dst[i]], 1);
}
__global__ void inv_kernel(const int* __restrict__ cnt, float* __restrict__ inv, int n) {
    int i = blockIdx.x * 256 + threadIdx.x;
    if (i < n) inv[i] = 1.0f / (float)max(cnt[i], 1);
}

// ---------- hierarchical exclusive scan over cnt[N] -> ofs[N+1] ----------
__global__ __launch_bounds__(SCAN_BLK) void scan_partial(const int* __restrict__ cnt,
                                                         int* __restrict__ ofs,
                                                         int* __restrict__ bsum) {
    __shared__ int sm[SCAN_BLK];
    int i = blockIdx.x * SCAN_BLK + threadIdx.x;
    int v = (i < N_NODESC) ? cnt[i] : 0;
    sm[threadIdx.x] = v;
    __syncthreads();
    for (int off = 1; off < SCAN_BLK; off <<= 1) {
        int t = (threadIdx.x >= off) ? sm[threadIdx.x - off] : 0;
        __syncthreads();
        sm[threadIdx.x] += t;
        __syncthreads();
    }
    if (i < N_NODESC) ofs[i] = sm[threadIdx.x] - v;  // exclusive within block
    if (threadIdx.x == SCAN_BLK - 1) bsum[blockIdx.x] = sm[SCAN_BLK - 1];
}

__global__ __launch_bounds__(128) void scan_bsums(int* __restrict__ bsum) {
    __shared__ int sm[SCAN_NBLK];
    if (threadIdx.x == 0) {
        int run = 0;
        for (int b = 0; b < SCAN_NBLK; ++b) {
            int t = bsum[b];
            sm[b] = run;
            run += t;
        }
        for (int b = 0; b < SCAN_NBLK; ++b) bsum[b] = sm[b];
    }
}

__global__ __launch_bounds__(SCAN_BLK) void scan_add(int* __restrict__ ofs,
                                                     const int* __restrict__ bsum) {
    int i = blockIdx.x * SCAN_BLK + threadIdx.x;
    if (i < N_NODESC) ofs[i] += bsum[blockIdx.x];
    if (i == 0) ofs[N_NODESC] = N_EDGESC;
}

// ---------- CSR fill ----------
__global__ void csr_fill(const int* __restrict__ src, const int* __restrict__ dst,
                         const int* __restrict__ ofs, int* __restrict__ cursor,
                         int* __restrict__ csr, int E) {
    int e = blockIdx.x * 256 + threadIdx.x;
    if (e < E) {
        int d = dst[e];
        int pos = atomicAdd(&cursor[d], 1);
        csr[ofs[d] + pos] = src[e];
    }
}

// ---------- graph ranges: boundary scan (batch sorted; no atomics) ----------
__global__ void ranges_bounds(const int* __restrict__ batch, int* __restrict__ gstart,
                              int* __restrict__ gend, int n) {
    int i = blockIdx.x * 256 + threadIdx.x;
    if (i >= n) return;
    int g = batch[i];
    if (i == 0 || batch[i - 1] != g) gstart[g] = i;
    if (i == n - 1 || batch[i + 1] != g) gend[g] = i + 1;
}

// ---------- weight transpose f32[256][256] -> bf16 WT[n][k] ----------
__global__ void wtransT(const float* __restrict__ W, unsigned short* __restrict__ WT) {
    __shared__ float t[16][17];
    int bx = blockIdx.x, by = blockIdx.y;
    int tx = threadIdx.x & 15, ty = threadIdx.x >> 4;
    t[ty][tx] = W[(by * 16 + ty) * HIDC + bx * 16 + tx];
    __syncthreads();
    WT[(size_t)(bx * 16 + ty) * HIDC + by * 16 + tx] = f2bf(t[tx][ty]);
}

// ---------- layer-1 mean gather (f32, 25 channels) ----------
__global__ void gather25(const float* __restrict__ x, const int* __restrict__ ofs,
                         const int* __restrict__ csr, const float* __restrict__ inv,
                         float* __restrict__ agg) {
    int idx = blockIdx.x * 256 + threadIdx.x;
    int node = idx >> 5, c = idx & 31;
    if (node >= N_NODESC || c >= IN_DIMC) return;
    float acc = 0.0f;
    int s = ofs[node], e = ofs[node + 1];
    for (int j = s; j < e; ++j) acc += x[(size_t)csr[j] * IN_DIMC + c];
    agg[(size_t)node * IN_DIMC + c] = acc * inv[node];
}

// ---------- hidden mean gather: one wave/node, half-wave/edge, 16B lanes ----------
__global__ void gather256(const unsigned short* __restrict__ h, const int* __restrict__ ofs,
                          const int* __restrict__ csr, const float* __restrict__ inv,
                          unsigned short* __restrict__ agg) {
    long long gtid = (long long)blockIdx.x * 256 + threadIdx.x;
    int node = (int)(gtid >> 6);
    if (node >= N_NODESC) return;
    const int lane = threadIdx.x & 63;
    const int half = lane >> 5;
    const int l = lane & 31;
    const int s = ofs[node], e = ofs[node + 1];

    float a0 = 0, a1 = 0, a2 = 0, a3 = 0, a4 = 0, a5 = 0, a6 = 0, a7 = 0;
    const size_t coff = (size_t)l * 8;

    int j = s + half;
    for (; j + 2 < e; j += 4) {
        int sn0 = csr[j];
        int sn1 = csr[j + 2];
        int4 v0 = *reinterpret_cast<const int4*>(h + (size_t)sn0 * HIDC + coff);
        int4 v1 = *reinterpret_cast<const int4*>(h + (size_t)sn1 * HIDC + coff);
        a0 += u2f(((unsigned)v0.x) << 16); a1 += u2f(((unsigned)v0.x) & 0xffff0000u);
        a2 += u2f(((unsigned)v0.y) << 16); a3 += u2f(((unsigned)v0.y) & 0xffff0000u);
        a4 += u2f(((unsigned)v0.z) << 16); a5 += u2f(((unsigned)v0.z) & 0xffff0000u);
        a6 += u2f(((unsigned)v0.w) << 16); a7 += u2f(((unsigned)v0.w) & 0xffff0000u);
        a0 += u2f(((unsigned)v1.x) << 16); a1 += u2f(((unsigned)v1.x) & 0xffff0000u);
        a2 += u2f(((unsigned)v1.y) << 16); a3 += u2f(((unsigned)v1.y) & 0xffff0000u);
        a4 += u2f(((unsigned)v1.z) << 16); a5 += u2f(((unsigned)v1.z) & 0xffff0000u);
        a6 += u2f(((unsigned)v1.w) << 16); a7 += u2f(((unsigned)v1.w) & 0xffff0000u);
    }
    if (j < e) {
        int sn0 = csr[j];
        int4 v0 = *reinterpret_cast<const int4*>(h + (size_t)sn0 * HIDC + coff);
        a0 += u2f(((unsigned)v0.x) << 16); a1 += u2f(((unsigned)v0.x) & 0xffff0000u);
        a2 += u2f(((unsigned)v0.y) << 16); a3 += u2f(((unsigned)v0.y) & 0xffff0000u);
        a4 += u2f(((unsigned)v0.z) << 16); a5 += u2f(((unsigned)v0.z) & 0xffff0000u);
        a6 += u2f(((unsigned)v0.w) << 16); a7 += u2f(((unsigned)v0.w) & 0xffff0000u);
    }

    a0 += __shfl_xor(a0, 32, 64); a1 += __shfl_xor(a1, 32, 64);
    a2 += __shfl_xor(a2, 32, 64); a3 += __shfl_xor(a3, 32, 64);
    a4 += __shfl_xor(a4, 32, 64); a5 += __shfl_xor(a5, 32, 64);
    a6 += __shfl_xor(a6, 32, 64); a7 += __shfl_xor(a7, 32, 64);

    if (half == 0) {
        float sc = inv[node];
        int4 p;
        p.x = (int)((unsigned)f2bf(a0 * sc) | ((unsigned)f2bf(a1 * sc) << 16));
        p.y = (int)((unsigned)f2bf(a2 * sc) | ((unsigned)f2bf(a3 * sc) << 16));
        p.z = (int)((unsigned)f2bf(a4 * sc) | ((unsigned)f2bf(a5 * sc) << 16));
        p.w = (int)((unsigned)f2bf(a6 * sc) | ((unsigned)f2bf(a7 * sc) << 16));
        *reinterpret_cast<int4*>(agg + (size_t)node * HIDC + coff) = p;
    }
}

// ---------- layer-1 f32 SAGE GEMM (K=25) ----------
template <int K>
__global__ __launch_bounds__(256) void sage_gemm_f32(
    const float* __restrict__ agg, const float* __restrict__ h,
    const float* __restrict__ Wl, const float* __restrict__ Wr,
    const float* __restrict__ bias,
    unsigned short* __restrict__ out, int nrows) {
    constexpr int BM = 64, BN = 64, BK = 16;
    __shared__ float sA[BK][BM + 4];
    __shared__ float sB[BK][BN + 4];
    const int tid = threadIdx.x;
    const int tx = tid & 15, ty = tid >> 4;
    const int rowbase = blockIdx.x * BM;
    const int colbase = blockIdx.y * BN;
    float acc[4][4] = {};
    const int lrow = tid >> 2, lkq = (tid & 3) * 4;
    const int lkB = tid >> 4, lnB = (tid & 15) * 4;

    for (int pass = 0; pass < 2; ++pass) {
        const float* __restrict__ A = pass ? h : agg;
        const float* __restrict__ W = pass ? Wr : Wl;
        const int grow = rowbase + lrow;
        for (int kb = 0; kb < K; kb += BK) {
#pragma unroll
            for (int j = 0; j < 4; ++j) {
                int k = kb + lkq + j;
                float v = 0.0f;
                if (grow < nrows && k < K) v = A[(size_t)grow * K + k];
                sA[lkq + j][lrow] = v;
            }
#pragma unroll
            for (int j = 0; j < 4; ++j) {
                int k = kb + lkB;
                int n = colbase + lnB + j;
                sB[lkB][lnB + j] = (k < K) ? W[(size_t)k * HIDC + n] : 0.0f;
            }
            __syncthreads();
#pragma unroll
            for (int kk = 0; kk < BK; ++kk) {
                float a[4], b[4];
#pragma unroll
                for (int i = 0; i < 4; ++i) a[i] = sA[kk][ty * 4 + i];
#pragma unroll
                for (int j = 0; j < 4; ++j) b[j] = sB[kk][tx * 4 + j];
#pragma unroll
                for (int i = 0; i < 4; ++i)
#pragma unroll
                    for (int j = 0; j < 4; ++j) acc[i][j] += a[i] * b[j];
            }
            __syncthreads();
        }
    }
#pragma unroll
    for (int i = 0; i < 4; ++i) {
        int r = rowbase + ty * 4 + i;
        if (r >= nrows) continue;
#pragma unroll
        for (int j = 0; j < 4; ++j) {
            int c = colbase + tx * 4 + j;
            out[(size_t)r * HIDC + c] = f2bf(fmaxf(acc[i][j] + bias[c], 0.0f));
        }
    }
}

// ---------- MFMA bf16 SAGE GEMM, m97-style: global_load_lds + XOR-swizzled LDS ----------
// out = relu(A0@B0 + A1@B1 + b). A: [M][256] bf16. BnT: [256 n][256 k] bf16.
// 256 threads = 4 waves; tile 64 rows x 256 cols (full-width => clean row writes).
// Per BK=64 step: DMA A(64x64, 8KB) + B(256x64, 32KB) to LDS via global_load_lds
// (linear dest, inverse-XOR-swizzled global source chunk), 2 barriers, then
// 2 k-groups x 16 MFMA per wave with XOR-swizzled ds_read_b128 (~2-way, free).
__global__ __launch_bounds__(256) void sage_gemm_mfma(
    const unsigned short* __restrict__ A0, const unsigned short* __restrict__ A1,
    const unsigned short* __restrict__ B0T, const unsigned short* __restrict__ B1T,
    const float* __restrict__ bias, unsigned short* __restrict__ out, int M) {
    constexpr int KD = 256;
    __shared__ unsigned short sA[64 * 64];   // [64 r][64 k] 8KB
    __shared__ unsigned short sB[256 * 64];  // [256 c][64 k] 32KB
    const int rowbase = blockIdx.x * 64;
    const int tid = threadIdx.x;
    const int lane = tid & 63;
    const int w = tid >> 6;  // wave 0..3 = col stripe
    const int fr = lane & 15;
    const int kq8 = (lane >> 4) << 3;  // 0,8,16,24 elems

    // staging lane geometry: each gload instr covers 8 rows x 128B (1024B)
    const int srow = lane >> 3;            // row within 8-row stripe
    const int schunk = (lane & 7) ^ srow;  // inverse-swizzled source 16B chunk

    f32x4 acc[4][4] = {};

    for (int pass = 0; pass < 2; ++pass) {
        const unsigned short* __restrict__ A = pass ? A1 : A0;
        const unsigned short* __restrict__ BT = pass ? B1T : B0T;
        for (int ks = 0; ks < 4; ++ks) {
            const int kb = ks * 64;
            __syncthreads();  // prior k-step frag reads done before overwrite
            // stage A: wave w covers rows w*16 .. w*16+15 (2 instrs)
#pragma unroll
            for (int c = 0; c < 2; ++c) {
                int ar = w * 16 + c * 8 + srow;
                const unsigned short* g = A + (size_t)(rowbase + ar) * KD + kb + (schunk << 3);
                __builtin_amdgcn_global_load_lds(
                    (const __attribute__((address_space(1))) void*)g,
                    (__attribute__((address_space(3))) void*)(sA + (w * 16 + c * 8) * 64),
                    16, 0, 0);
            }
            // stage B: wave w covers cols w*64 .. w*64+63 (8 instrs)
#pragma unroll
            for (int c = 0; c < 8; ++c) {
                int br = w * 64 + c * 8 + srow;
                const unsigned short* g = BT + (size_t)br * KD + kb + (schunk << 3);
                __builtin_amdgcn_global_load_lds(
                    (const __attribute__((address_space(1))) void*)g,
                    (__attribute__((address_space(3))) void*)(sB + (w * 64 + c * 8) * 64),
                    16, 0, 0);
            }
            __syncthreads();  // vmcnt drained here -> LDS ready
#pragma unroll
            for (int kg = 0; kg < 2; ++kg) {
                bf16x8 af[4], bfr[4];
#pragma unroll
                for (int t = 0; t < 4; ++t) {
                    int ra = t * 16 + fr;
                    int ba = ra * 128 + ((kg * 64 + kq8 * 2) ^ ((ra & 7) << 4));
                    af[t] = *reinterpret_cast<const bf16x8*>(
                        reinterpret_cast<const char*>(sA) + ba);
                    int rb = w * 64 + t * 16 + fr;
                    int bb2 = rb * 128 + ((kg * 64 + kq8 * 2) ^ ((rb & 7) << 4));
                    bfr[t] = *reinterpret_cast<const bf16x8*>(
                        reinterpret_cast<const char*>(sB) + bb2);
                }
#pragma unroll
                for (int i = 0; i < 4; ++i)
#pragma unroll
                    for (int j = 0; j < 4; ++j)
                        acc[i][j] = __builtin_amdgcn_mfma_f32_16x16x32_bf16(
                            af[i], bfr[j], acc[i][j], 0, 0, 0);
            }
        }
    }

    // epilogue: C/D layout col=lane&15, row=4*(lane>>4)+r
    const int crow0 = (lane >> 4) << 2;
#pragma unroll
    for (int i = 0; i < 4; ++i) {
#pragma unroll
        for (int j = 0; j < 4; ++j) {
            int col = w * 64 + j * 16 + fr;
            float bb = bias[col];
#pragma unroll
            for (int r = 0; r < 4; ++r) {
                int row = rowbase + i * 16 + crow0 + r;
                if (row < M)
                    out[(size_t)row * HIDC + col] = f2bf(fmaxf(acc[i][j][r] + bb, 0.0f));
            }
        }
    }
}

// ---------- segment-max pool: 8-way parallel per graph, atomicMax (values >= 0) ----------
__global__ void pool_max(const unsigned short* __restrict__ h, const int* __restrict__ gstart,
                         const int* __restrict__ gend, float* __restrict__ xc, int col_off) {
    int g = blockIdx.x;
    int chunk = blockIdx.y;  // 0..7
    int c = threadIdx.x;
    int s = gstart[g], e = gend[g];
    int len = e - s;
    if (len <= 0) return;
    int per = (len + 7) >> 3;
    int cs = s + chunk * per;
    int ce = min(cs + per, e);
    if (cs >= ce) return;
    float m = 0.0f;  // relu outputs >= 0
    for (int i = cs; i < ce; ++i) m = fmaxf(m, bf2f(h[(size_t)i * HIDC + c]));
    atomicMax(reinterpret_cast<int*>(&xc[(size_t)g * (3 * HIDC) + col_off + c]),
              __float_as_int(m));
}

// ---------- head MLPs ----------
__global__ void mlp1(const float* __restrict__ xc, const float* __restrict__ W,
                     const float* __restrict__ b, float* __restrict__ hmid) {
    __shared__ float row[3 * HIDC];
    int g = blockIdx.x;
    for (int i = threadIdx.x; i < 3 * HIDC; i += 256) row[i] = xc[(size_t)g * (3 * HIDC) + i];
    __syncthreads();
    float acc = b[threadIdx.x];
    for (int k = 0; k < 3 * HIDC; ++k) acc += row[k] * W[(size_t)k * HIDC + threadIdx.x];
    hmid[(size_t)g * HIDC + threadIdx.x] = fmaxf(acc, 0.0f);
}

__global__ void mlp2(const float* __restrict__ hmid, const float* __restrict__ W,
                     const float* __restrict__ b, float* __restrict__ out) {
    __shared__ float row[HIDC];
    int g = blockIdx.x;
    for (int i = threadIdx.x; i < HIDC; i += 128) row[i] = hmid[(size_t)g * HIDC + i];
    __syncthreads();
    float acc = b[threadIdx.x];
    for (int k = 0; k < HIDC; ++k) acc += row[k] * W[(size_t)k * OUT_DIMC + threadIdx.x];
    out[(size_t)g * OUT_DIMC + threadIdx.x] = acc;
}

static inline char* align_up(char* p, size_t a) {
    return (char*)(((uintptr_t)p + a - 1) & ~(uintptr_t)(a - 1));
}

extern "C" void kernel_launch(void* const* d_in, const int* in_sizes, int n_in,
                              void* d_out, int out_size, void* d_ws, size_t ws_size,
                              hipStream_t stream) {
    const float* x = (const float*)d_in[0];
    const int* edge_index = (const int*)d_in[1];
    const int* batch = (const int*)d_in[2];
    const float* W1l = (const float*)d_in[3];
    const float* W1r = (const float*)d_in[4];
    const float* b1 = (const float*)d_in[5];
    const float* W2l = (const float*)d_in[6];
    const float* W2r = (const float*)d_in[7];
    const float* b2 = (const float*)d_in[8];
    const float* W3l = (const float*)d_in[9];
    const float* W3r = (const float*)d_in[10];
    const float* b3 = (const float*)d_in[11];
    const float* Wlin1 = (const float*)d_in[12];
    const float* blin1 = (const float*)d_in[13];
    const float* Wlin2 = (const float*)d_in[14];
    const float* blin2 = (const float*)d_in[15];
    float* out = (float*)d_out;

    const int N = N_NODESC, E = N_EDGESC;
    const int* src = edge_index;
    const int* dst = edge_index + E;

    // ---- workspace carve-up ----
    char* w0 = (char*)d_ws;
    char* w = w0;
    int* cnt = (int*)w;        w = align_up(w + (size_t)N * 4, 256);
    float* invc = (float*)w;   w = align_up(w + (size_t)N * 4, 256);
    int* row_ofs = (int*)w;    w = align_up(w + (size_t)(N + 1) * 4, 256);
    int* bsum = (int*)w;       w = align_up(w + (size_t)SCAN_NBLK * 4, 256);
    int* csr = (int*)w;        w = align_up(w + (size_t)E * 4, 256);
    int* gstart = (int*)w;     w = align_up(w + (size_t)N_GRAPHSC * 4, 256);
    int* gend = (int*)w;       w = align_up(w + (size_t)N_GRAPHSC * 4, 256);
    float* xc = (float*)w;     w = align_up(w + (size_t)N_GRAPHSC * 3 * HIDC * 4, 256);
    float* hmid = (float*)w;   w = align_up(w + (size_t)N_GRAPHSC * HIDC * 4, 256);
    unsigned short* W2lT = (unsigned short*)w; w = align_up(w + (size_t)HIDC * HIDC * 2, 256);
    unsigned short* W2rT = (unsigned short*)w; w = align_up(w + (size_t)HIDC * HIDC * 2, 256);
    unsigned short* W3lT = (unsigned short*)w; w = align_up(w + (size_t)HIDC * HIDC * 2, 256);
    unsigned short* W3rT = (unsigned short*)w; w = align_up(w + (size_t)HIDC * HIDC * 2, 256);
    char* aggU = w;            w = align_up(w + (size_t)N * HIDC * 2, 256);
    unsigned short* h1 = (unsigned short*)w;  w = align_up(w + (size_t)N * HIDC * 2, 256);
    unsigned short* h2 = (unsigned short*)w;  w = align_up(w + (size_t)N * HIDC * 2 + 65536, 256);
    size_t required = (size_t)(w - w0);
    if (ws_size < required) return;

    float* agg25 = (float*)aggU;
    unsigned short* aggH = (unsigned short*)aggU;

    const int nbN = (N + 255) / 256;
    const int nbE = (E + 255) / 256;
    const dim3 gemm_grid_f32((N + 63) / 64, HIDC / 64);
    const dim3 tgrid(16, 16);
    const dim3 pgrid(N_GRAPHSC, 8);

    // weight transposes
    wtransT<<<tgrid, 256, 0, stream>>>(W2l, W2lT);
    wtransT<<<tgrid, 256, 0, stream>>>(W2r, W2rT);
    wtransT<<<tgrid, 256, 0, stream>>>(W3l, W3lT);
    wtransT<<<tgrid, 256, 0, stream>>>(W3r, W3rT);

    // degrees + inv
    fill_u32<<<nbN, 256, 0, stream>>>((unsigned*)cnt, 0u, N);
    deg_kernel<<<nbE, 256, 0, stream>>>(dst, cnt, E);
    inv_kernel<<<nbN, 256, 0, stream>>>(cnt, invc, N);
    // CSR offsets: hierarchical scan
    scan_partial<<<SCAN_NBLK, SCAN_BLK, 0, stream>>>(cnt, row_ofs, bsum);
    scan_bsums<<<1, 128, 0, stream>>>(bsum);
    scan_add<<<SCAN_NBLK, SCAN_BLK, 0, stream>>>(row_ofs, bsum);
    fill_u32<<<nbN, 256, 0, stream>>>((unsigned*)cnt, 0u, N);
    csr_fill<<<nbE, 256, 0, stream>>>(src, dst, row_ofs, cnt, csr, E);
    // graph ranges + zero xc (pool uses atomicMax over non-negative floats)
    fill_u32<<<1, 256, 0, stream>>>((unsigned*)gstart, (unsigned)N, N_GRAPHSC);
    fill_u32<<<1, 256, 0, stream>>>((unsigned*)gend, 0u, N_GRAPHSC);
    ranges_bounds<<<nbN, 256, 0, stream>>>(batch, gstart, gend, N);
    fill_u32<<<(N_GRAPHSC * 3 * HIDC + 255) / 256, 256, 0, stream>>>((unsigned*)xc, 0u,
                                                                     N_GRAPHSC * 3 * HIDC);

    // ---- layer 1 (K=25, f32) ----
    gather25<<<(N * 32 + 255) / 256, 256, 0, stream>>>(x, row_ofs, csr, invc, agg25);
    sage_gemm_f32<IN_DIMC><<<gemm_grid_f32, 256, 0, stream>>>(agg25, x, W1l, W1r, b1, h1, N);
    pool_max<<<pgrid, 256, 0, stream>>>(h1, gstart, gend, xc, 0);

    // ---- layer 2 (MFMA, gload_lds) ----
    gather256<<<(N * 64 + 255) / 256, 256, 0, stream>>>(h1, row_ofs, csr, invc, aggH);
    sage_gemm_mfma<<<NRB64, 256, 0, stream>>>(aggH, h1, W2lT, W2rT, b2, h2, N);
    pool_max<<<pgrid, 256, 0, stream>>>(h2, gstart, gend, xc, HIDC);

    // ---- layer 3 (MFMA, gload_lds) ----
    gather256<<<(N * 64 + 255) / 256, 256, 0, stream>>>(h2, row_ofs, csr, invc, aggH);
    sage_gemm_mfma<<<NRB64, 256, 0, stream>>>(aggH, h2, W3lT, W3rT, b3, h1, N);
    pool_max<<<pgrid, 256, 0, stream>>>(h1, gstart, gend, xc, 2 * HIDC);

    // ---- head ----
    mlp1<<<N_GRAPHSC, 256, 0, stream>>>(xc, Wlin1, blin1, hmid);
    mlp2<<<N_GRAPHSC, 128, 0, stream>>>(hmid, Wlin2, blin2, out);
}

// Round 12
// 672.517 us; speedup vs baseline: 1.9325x; 1.1556x over previous
//
#include <hip/hip_runtime.h>
#include <hip/hip_bf16.h>

#define N_NODESC 100000
#define N_EDGESC 1600000
#define N_GRAPHSC 200
#define IN_DIMC 25
#define HIDC 256
#define OUT_DIMC 128
#define SCAN_BLK 1024
#define SCAN_NBLK ((N_NODESC + SCAN_BLK - 1) / SCAN_BLK)
#define NRB64 ((N_NODESC + 63) / 64)  // 1563 row-blocks
#define NBKT ((N_NODESC + 255) / 256)  // 391 dst-buckets (256 nodes each)
#define NCH 400                        // edge chunks
#define CHSZ (N_EDGESC / NCH)          // 4000 edges/chunk (exact)

typedef __attribute__((ext_vector_type(8))) short bf16x8;
typedef __attribute__((ext_vector_type(4))) float f32x4;

// ---------- bf16 helpers (raw ushort storage) ----------
__device__ inline float bf2f(unsigned short u) {
    union { float f; unsigned u32; } c;
    c.u32 = ((unsigned)u) << 16;
    return c.f;
}
__device__ inline unsigned short f2bf(float f) {
    union { float f; unsigned u; } c;
    c.f = f;
    unsigned r = (c.u + 0x7FFFu + ((c.u >> 16) & 1u)) >> 16;  // RNE
    return (unsigned short)r;
}
__device__ inline float u2f(unsigned u) {
    union { unsigned u; float f; } c;
    c.u = u;
    return c.f;
}

// ---------- utility fills ----------
__global__ void fill_u32(unsigned* __restrict__ p, unsigned v, int n) {
    int i = blockIdx.x * 256 + threadIdx.x;
    if (i < n) p[i] = v;
}

__global__ void inv_kernel(const int* __restrict__ cnt, float* __restrict__ inv, int n) {
    int i = blockIdx.x * 256 + threadIdx.x;
    if (i < n) inv[i] = 1.0f / (float)max(cnt[i], 1);
}

// ---------- bucketed CSR build ----------
// Pass A: per-chunk histogram over dst>>8
__global__ __launch_bounds__(256) void hist_kernel(const int* __restrict__ dst,
                                                   int* __restrict__ hist) {
    __shared__ int h[NBKT];
    const int c = blockIdx.x, tid = threadIdx.x;
    for (int t = tid; t < NBKT; t += 256) h[t] = 0;
    __syncthreads();
    const int e0 = c * CHSZ;
    for (int e = e0 + tid; e < e0 + CHSZ; e += 256) atomicAdd(&h[dst[e] >> 8], 1);
    __syncthreads();
    for (int t = tid; t < NBKT; t += 256) hist[c * NBKT + t] = h[t];
}

// Pass B: in-place bucket-major exclusive scan of hist; base[b] = bucket starts
__global__ __launch_bounds__(512) void scan_hist(int* __restrict__ hist,
                                                 int* __restrict__ base) {
    __shared__ int sm[512];
    const int tid = threadIdx.x;
    int v = 0;
    if (tid < NBKT)
        for (int c = 0; c < NCH; ++c) v += hist[c * NBKT + tid];
    sm[tid] = v;
    __syncthreads();
    for (int off = 1; off < 512; off <<= 1) {
        int t = (tid >= off) ? sm[tid - off] : 0;
        __syncthreads();
        sm[tid] += t;
        __syncthreads();
    }
    int excl = sm[tid] - v;
    if (tid <= NBKT) base[tid] = excl;  // base[NBKT] == E
    if (tid < NBKT) {
        int run = excl;
        for (int c = 0; c < NCH; ++c) {
            int t = hist[c * NBKT + tid];
            hist[c * NBKT + tid] = run;
            run += t;
        }
    }
}

// Pass C: scatter (src,dst) pairs bucket-sorted
__global__ __launch_bounds__(256) void bucket_scatter(const int* __restrict__ src,
                                                      const int* __restrict__ dst,
                                                      const int* __restrict__ ofs2,
                                                      int2* __restrict__ pairs) {
    __shared__ int cur[NBKT];
    __shared__ int o2[NBKT];
    const int c = blockIdx.x, tid = threadIdx.x;
    for (int t = tid; t < NBKT; t += 256) {
        cur[t] = 0;
        o2[t] = ofs2[c * NBKT + t];
    }
    __syncthreads();
    const int e0 = c * CHSZ;
    for (int e = e0 + tid; e < e0 + CHSZ; e += 256) {
        int s = src[e], d = dst[e];
        int b = d >> 8;
        int p = atomicAdd(&cur[b], 1);
        pairs[o2[b] + p] = make_int2(s, d);
    }
}

// Pass D0: per-node degree from bucket-sorted pairs (coalesced output)
__global__ __launch_bounds__(256) void bucket_deg(const int2* __restrict__ pairs,
                                                  const int* __restrict__ base,
                                                  int* __restrict__ cnt) {
    __shared__ int h[256];
    const int b = blockIdx.x, tid = threadIdx.x;
    h[tid] = 0;
    __syncthreads();
    for (int i = base[b] + tid; i < base[b + 1]; i += 256)
        atomicAdd(&h[pairs[i].y & 255], 1);
    __syncthreads();
    int node = b * 256 + tid;
    if (node < N_NODESC) cnt[node] = h[tid];
}

// Pass D1: csr fill, writes confined to one ~16KB window per block
__global__ __launch_bounds__(256) void bucket_csrfill(const int2* __restrict__ pairs,
                                                      const int* __restrict__ base,
                                                      const int* __restrict__ row_ofs,
                                                      int* __restrict__ csr) {
    __shared__ int cur[256];
    __shared__ int ob[256];
    const int b = blockIdx.x, tid = threadIdx.x;
    int node = b * 256 + tid;
    ob[tid] = (node < N_NODESC) ? row_ofs[node] : 0;
    cur[tid] = 0;
    __syncthreads();
    for (int i = base[b] + tid; i < base[b + 1]; i += 256) {
        int2 pr = pairs[i];
        int loc = pr.y & 255;
        int p = atomicAdd(&cur[loc], 1);
        csr[ob[loc] + p] = pr.x;
    }
}

// ---------- hierarchical exclusive scan over cnt[N] -> ofs[N+1] ----------
__global__ __launch_bounds__(SCAN_BLK) void scan_partial(const int* __restrict__ cnt,
                                                         int* __restrict__ ofs,
                                                         int* __restrict__ bsum) {
    __shared__ int sm[SCAN_BLK];
    int i = blockIdx.x * SCAN_BLK + threadIdx.x;
    int v = (i < N_NODESC) ? cnt[i] : 0;
    sm[threadIdx.x] = v;
    __syncthreads();
    for (int off = 1; off < SCAN_BLK; off <<= 1) {
        int t = (threadIdx.x >= off) ? sm[threadIdx.x - off] : 0;
        __syncthreads();
        sm[threadIdx.x] += t;
        __syncthreads();
    }
    if (i < N_NODESC) ofs[i] = sm[threadIdx.x] - v;  // exclusive within block
    if (threadIdx.x == SCAN_BLK - 1) bsum[blockIdx.x] = sm[SCAN_BLK - 1];
}

__global__ __launch_bounds__(128) void scan_bsums(int* __restrict__ bsum) {
    __shared__ int sm[SCAN_NBLK];
    if (threadIdx.x == 0) {
        int run = 0;
        for (int b = 0; b < SCAN_NBLK; ++b) {
            int t = bsum[b];
            sm[b] = run;
            run += t;
        }
        for (int b = 0; b < SCAN_NBLK; ++b) bsum[b] = sm[b];
    }
}

__global__ __launch_bounds__(SCAN_BLK) void scan_add(int* __restrict__ ofs,
                                                     const int* __restrict__ bsum) {
    int i = blockIdx.x * SCAN_BLK + threadIdx.x;
    if (i < N_NODESC) ofs[i] += bsum[blockIdx.x];
    if (i == 0) ofs[N_NODESC] = N_EDGESC;
}

// ---------- graph ranges: boundary scan (batch sorted; no atomics) ----------
__global__ void ranges_bounds(const int* __restrict__ batch, int* __restrict__ gstart,
                              int* __restrict__ gend, int n) {
    int i = blockIdx.x * 256 + threadIdx.x;
    if (i >= n) return;
    int g = batch[i];
    if (i == 0 || batch[i - 1] != g) gstart[g] = i;
    if (i == n - 1 || batch[i + 1] != g) gend[g] = i + 1;
}

// ---------- weight transpose f32[256][256] -> bf16 WT[n][k] ----------
__global__ void wtransT(const float* __restrict__ W, unsigned short* __restrict__ WT) {
    __shared__ float t[16][17];
    int bx = blockIdx.x, by = blockIdx.y;
    int tx = threadIdx.x & 15, ty = threadIdx.x >> 4;
    t[ty][tx] = W[(by * 16 + ty) * HIDC + bx * 16 + tx];
    __syncthreads();
    WT[(size_t)(bx * 16 + ty) * HIDC + by * 16 + tx] = f2bf(t[tx][ty]);
}

// ---------- layer-1 mean gather (f32, 25 channels) ----------
__global__ void gather25(const float* __restrict__ x, const int* __restrict__ ofs,
                         const int* __restrict__ csr, const float* __restrict__ inv,
                         float* __restrict__ agg) {
    int idx = blockIdx.x * 256 + threadIdx.x;
    int node = idx >> 5, c = idx & 31;
    if (node >= N_NODESC || c >= IN_DIMC) return;
    float acc = 0.0f;
    int s = ofs[node], e = ofs[node + 1];
    for (int j = s; j < e; ++j) acc += x[(size_t)csr[j] * IN_DIMC + c];
    agg[(size_t)node * IN_DIMC + c] = acc * inv[node];
}

// ---------- hidden mean gather: one wave/node, half-wave/edge, 16B lanes ----------
__global__ void gather256(const unsigned short* __restrict__ h, const int* __restrict__ ofs,
                          const int* __restrict__ csr, const float* __restrict__ inv,
                          unsigned short* __restrict__ agg) {
    long long gtid = (long long)blockIdx.x * 256 + threadIdx.x;
    int node = (int)(gtid >> 6);
    if (node >= N_NODESC) return;
    const int lane = threadIdx.x & 63;
    const int half = lane >> 5;
    const int l = lane & 31;
    const int s = ofs[node], e = ofs[node + 1];

    float a0 = 0, a1 = 0, a2 = 0, a3 = 0, a4 = 0, a5 = 0, a6 = 0, a7 = 0;
    const size_t coff = (size_t)l * 8;

    int j = s + half;
    for (; j + 2 < e; j += 4) {
        int sn0 = csr[j];
        int sn1 = csr[j + 2];
        int4 v0 = *reinterpret_cast<const int4*>(h + (size_t)sn0 * HIDC + coff);
        int4 v1 = *reinterpret_cast<const int4*>(h + (size_t)sn1 * HIDC + coff);
        a0 += u2f(((unsigned)v0.x) << 16); a1 += u2f(((unsigned)v0.x) & 0xffff0000u);
        a2 += u2f(((unsigned)v0.y) << 16); a3 += u2f(((unsigned)v0.y) & 0xffff0000u);
        a4 += u2f(((unsigned)v0.z) << 16); a5 += u2f(((unsigned)v0.z) & 0xffff0000u);
        a6 += u2f(((unsigned)v0.w) << 16); a7 += u2f(((unsigned)v0.w) & 0xffff0000u);
        a0 += u2f(((unsigned)v1.x) << 16); a1 += u2f(((unsigned)v1.x) & 0xffff0000u);
        a2 += u2f(((unsigned)v1.y) << 16); a3 += u2f(((unsigned)v1.y) & 0xffff0000u);
        a4 += u2f(((unsigned)v1.z) << 16); a5 += u2f(((unsigned)v1.z) & 0xffff0000u);
        a6 += u2f(((unsigned)v1.w) << 16); a7 += u2f(((unsigned)v1.w) & 0xffff0000u);
    }
    if (j < e) {
        int sn0 = csr[j];
        int4 v0 = *reinterpret_cast<const int4*>(h + (size_t)sn0 * HIDC + coff);
        a0 += u2f(((unsigned)v0.x) << 16); a1 += u2f(((unsigned)v0.x) & 0xffff0000u);
        a2 += u2f(((unsigned)v0.y) << 16); a3 += u2f(((unsigned)v0.y) & 0xffff0000u);
        a4 += u2f(((unsigned)v0.z) << 16); a5 += u2f(((unsigned)v0.z) & 0xffff0000u);
        a6 += u2f(((unsigned)v0.w) << 16); a7 += u2f(((unsigned)v0.w) & 0xffff0000u);
    }

    a0 += __shfl_xor(a0, 32, 64); a1 += __shfl_xor(a1, 32, 64);
    a2 += __shfl_xor(a2, 32, 64); a3 += __shfl_xor(a3, 32, 64);
    a4 += __shfl_xor(a4, 32, 64); a5 += __shfl_xor(a5, 32, 64);
    a6 += __shfl_xor(a6, 32, 64); a7 += __shfl_xor(a7, 32, 64);

    if (half == 0) {
        float sc = inv[node];
        int4 p;
        p.x = (int)((unsigned)f2bf(a0 * sc) | ((unsigned)f2bf(a1 * sc) << 16));
        p.y = (int)((unsigned)f2bf(a2 * sc) | ((unsigned)f2bf(a3 * sc) << 16));
        p.z = (int)((unsigned)f2bf(a4 * sc) | ((unsigned)f2bf(a5 * sc) << 16));
        p.w = (int)((unsigned)f2bf(a6 * sc) | ((unsigned)f2bf(a7 * sc) << 16));
        *reinterpret_cast<int4*>(agg + (size_t)node * HIDC + coff) = p;
    }
}

// ---------- layer-1 f32 SAGE GEMM (K=25) ----------
template <int K>
__global__ __launch_bounds__(256) void sage_gemm_f32(
    const float* __restrict__ agg, const float* __restrict__ h,
    const float* __restrict__ Wl, const float* __restrict__ Wr,
    const float* __restrict__ bias,
    unsigned short* __restrict__ out, int nrows) {
    constexpr int BM = 64, BN = 64, BK = 16;
    __shared__ float sA[BK][BM + 4];
    __shared__ float sB[BK][BN + 4];
    const int tid = threadIdx.x;
    const int tx = tid & 15, ty = tid >> 4;
    const int rowbase = blockIdx.x * BM;
    const int colbase = blockIdx.y * BN;
    float acc[4][4] = {};
    const int lrow = tid >> 2, lkq = (tid & 3) * 4;
    const int lkB = tid >> 4, lnB = (tid & 15) * 4;

    for (int pass = 0; pass < 2; ++pass) {
        const float* __restrict__ A = pass ? h : agg;
        const float* __restrict__ W = pass ? Wr : Wl;
        const int grow = rowbase + lrow;
        for (int kb = 0; kb < K; kb += BK) {
#pragma unroll
            for (int j = 0; j < 4; ++j) {
                int k = kb + lkq + j;
                float v = 0.0f;
                if (grow < nrows && k < K) v = A[(size_t)grow * K + k];
                sA[lkq + j][lrow] = v;
            }
#pragma unroll
            for (int j = 0; j < 4; ++j) {
                int k = kb + lkB;
                int n = colbase + lnB + j;
                sB[lkB][lnB + j] = (k < K) ? W[(size_t)k * HIDC + n] : 0.0f;
            }
            __syncthreads();
#pragma unroll
            for (int kk = 0; kk < BK; ++kk) {
                float a[4], b[4];
#pragma unroll
                for (int i = 0; i < 4; ++i) a[i] = sA[kk][ty * 4 + i];
#pragma unroll
                for (int j = 0; j < 4; ++j) b[j] = sB[kk][tx * 4 + j];
#pragma unroll
                for (int i = 0; i < 4; ++i)
#pragma unroll
                    for (int j = 0; j < 4; ++j) acc[i][j] += a[i] * b[j];
            }
            __syncthreads();
        }
    }
#pragma unroll
    for (int i = 0; i < 4; ++i) {
        int r = rowbase + ty * 4 + i;
        if (r >= nrows) continue;
#pragma unroll
        for (int j = 0; j < 4; ++j) {
            int c = colbase + tx * 4 + j;
            out[(size_t)r * HIDC + c] = f2bf(fmaxf(acc[i][j] + bias[c], 0.0f));
        }
    }
}

// ---------- MFMA bf16 SAGE GEMM, m97-style: global_load_lds + XOR-swizzled LDS ----------
__global__ __launch_bounds__(256) void sage_gemm_mfma(
    const unsigned short* __restrict__ A0, const unsigned short* __restrict__ A1,
    const unsigned short* __restrict__ B0T, const unsigned short* __restrict__ B1T,
    const float* __restrict__ bias, unsigned short* __restrict__ out, int M) {
    constexpr int KD = 256;
    __shared__ unsigned short sA[64 * 64];   // [64 r][64 k] 8KB
    __shared__ unsigned short sB[256 * 64];  // [256 c][64 k] 32KB
    const int rowbase = blockIdx.x * 64;
    const int tid = threadIdx.x;
    const int lane = tid & 63;
    const int w = tid >> 6;  // wave 0..3 = col stripe
    const int fr = lane & 15;
    const int kq8 = (lane >> 4) << 3;  // 0,8,16,24 elems

    const int srow = lane >> 3;            // row within 8-row stripe
    const int schunk = (lane & 7) ^ srow;  // inverse-swizzled source 16B chunk

    f32x4 acc[4][4] = {};

    for (int pass = 0; pass < 2; ++pass) {
        const unsigned short* __restrict__ A = pass ? A1 : A0;
        const unsigned short* __restrict__ BT = pass ? B1T : B0T;
        for (int ks = 0; ks < 4; ++ks) {
            const int kb = ks * 64;
            __syncthreads();  // prior k-step frag reads done before overwrite
#pragma unroll
            for (int c = 0; c < 2; ++c) {
                int ar = w * 16 + c * 8 + srow;
                const unsigned short* g = A + (size_t)(rowbase + ar) * KD + kb + (schunk << 3);
                __builtin_amdgcn_global_load_lds(
                    (const __attribute__((address_space(1))) void*)g,
                    (__attribute__((address_space(3))) void*)(sA + (w * 16 + c * 8) * 64),
                    16, 0, 0);
            }
#pragma unroll
            for (int c = 0; c < 8; ++c) {
                int br = w * 64 + c * 8 + srow;
                const unsigned short* g = BT + (size_t)br * KD + kb + (schunk << 3);
                __builtin_amdgcn_global_load_lds(
                    (const __attribute__((address_space(1))) void*)g,
                    (__attribute__((address_space(3))) void*)(sB + (w * 64 + c * 8) * 64),
                    16, 0, 0);
            }
            __syncthreads();  // vmcnt drained here -> LDS ready
#pragma unroll
            for (int kg = 0; kg < 2; ++kg) {
                bf16x8 af[4], bfr[4];
#pragma unroll
                for (int t = 0; t < 4; ++t) {
                    int ra = t * 16 + fr;
                    int ba = ra * 128 + ((kg * 64 + kq8 * 2) ^ ((ra & 7) << 4));
                    af[t] = *reinterpret_cast<const bf16x8*>(
                        reinterpret_cast<const char*>(sA) + ba);
                    int rb = w * 64 + t * 16 + fr;
                    int bb2 = rb * 128 + ((kg * 64 + kq8 * 2) ^ ((rb & 7) << 4));
                    bfr[t] = *reinterpret_cast<const bf16x8*>(
                        reinterpret_cast<const char*>(sB) + bb2);
                }
#pragma unroll
                for (int i = 0; i < 4; ++i)
#pragma unroll
                    for (int j = 0; j < 4; ++j)
                        acc[i][j] = __builtin_amdgcn_mfma_f32_16x16x32_bf16(
                            af[i], bfr[j], acc[i][j], 0, 0, 0);
            }
        }
    }

    const int crow0 = (lane >> 4) << 2;
#pragma unroll
    for (int i = 0; i < 4; ++i) {
#pragma unroll
        for (int j = 0; j < 4; ++j) {
            int col = w * 64 + j * 16 + fr;
            float bb = bias[col];
#pragma unroll
            for (int r = 0; r < 4; ++r) {
                int row = rowbase + i * 16 + crow0 + r;
                if (row < M)
                    out[(size_t)row * HIDC + col] = f2bf(fmaxf(acc[i][j][r] + bb, 0.0f));
            }
        }
    }
}

// ---------- segment-max pool: 8-way parallel per graph, atomicMax (values >= 0) ----------
__global__ void pool_max(const unsigned short* __restrict__ h, const int* __restrict__ gstart,
                         const int* __restrict__ gend, float* __restrict__ xc, int col_off) {
    int g = blockIdx.x;
    int chunk = blockIdx.y;  // 0..7
    int c = threadIdx.x;
    int s = gstart[g], e = gend[g];
    int len = e - s;
    if (len <= 0) return;
    int per = (len + 7) >> 3;
    int cs = s + chunk * per;
    int ce = min(cs + per, e);
    if (cs >= ce) return;
    float m = 0.0f;  // relu outputs >= 0
    for (int i = cs; i < ce; ++i) m = fmaxf(m, bf2f(h[(size_t)i * HIDC + c]));
    atomicMax(reinterpret_cast<int*>(&xc[(size_t)g * (3 * HIDC) + col_off + c]),
              __float_as_int(m));
}

// ---------- head MLPs ----------
__global__ void mlp1(const float* __restrict__ xc, const float* __restrict__ W,
                     const float* __restrict__ b, float* __restrict__ hmid) {
    __shared__ float row[3 * HIDC];
    int g = blockIdx.x;
    for (int i = threadIdx.x; i < 3 * HIDC; i += 256) row[i] = xc[(size_t)g * (3 * HIDC) + i];
    __syncthreads();
    float acc = b[threadIdx.x];
    for (int k = 0; k < 3 * HIDC; ++k) acc += row[k] * W[(size_t)k * HIDC + threadIdx.x];
    hmid[(size_t)g * HIDC + threadIdx.x] = fmaxf(acc, 0.0f);
}

__global__ void mlp2(const float* __restrict__ hmid, const float* __restrict__ W,
                     const float* __restrict__ b, float* __restrict__ out) {
    __shared__ float row[HIDC];
    int g = blockIdx.x;
    for (int i = threadIdx.x; i < HIDC; i += 128) row[i] = hmid[(size_t)g * HIDC + i];
    __syncthreads();
    float acc = b[threadIdx.x];
    for (int k = 0; k < HIDC; ++k) acc += row[k] * W[(size_t)k * OUT_DIMC + threadIdx.x];
    out[(size_t)g * OUT_DIMC + threadIdx.x] = acc;
}

static inline char* align_up(char* p, size_t a) {
    return (char*)(((uintptr_t)p + a - 1) & ~(uintptr_t)(a - 1));
}

extern "C" void kernel_launch(void* const* d_in, const int* in_sizes, int n_in,
                              void* d_out, int out_size, void* d_ws, size_t ws_size,
                              hipStream_t stream) {
    const float* x = (const float*)d_in[0];
    const int* edge_index = (const int*)d_in[1];
    const int* batch = (const int*)d_in[2];
    const float* W1l = (const float*)d_in[3];
    const float* W1r = (const float*)d_in[4];
    const float* b1 = (const float*)d_in[5];
    const float* W2l = (const float*)d_in[6];
    const float* W2r = (const float*)d_in[7];
    const float* b2 = (const float*)d_in[8];
    const float* W3l = (const float*)d_in[9];
    const float* W3r = (const float*)d_in[10];
    const float* b3 = (const float*)d_in[11];
    const float* Wlin1 = (const float*)d_in[12];
    const float* blin1 = (const float*)d_in[13];
    const float* Wlin2 = (const float*)d_in[14];
    const float* blin2 = (const float*)d_in[15];
    float* out = (float*)d_out;

    const int N = N_NODESC, E = N_EDGESC;
    const int* src = edge_index;
    const int* dst = edge_index + E;

    // ---- workspace carve-up ----
    char* w0 = (char*)d_ws;
    char* w = w0;
    int* cnt = (int*)w;        w = align_up(w + (size_t)N * 4, 256);
    float* invc = (float*)w;   w = align_up(w + (size_t)N * 4, 256);
    int* row_ofs = (int*)w;    w = align_up(w + (size_t)(N + 1) * 4, 256);
    int* bsum = (int*)w;       w = align_up(w + (size_t)SCAN_NBLK * 4, 256);
    int* bbase = (int*)w;      w = align_up(w + (size_t)(NBKT + 1) * 4, 256);
    int* csr = (int*)w;        w = align_up(w + (size_t)E * 4, 256);
    int* gstart = (int*)w;     w = align_up(w + (size_t)N_GRAPHSC * 4, 256);
    int* gend = (int*)w;       w = align_up(w + (size_t)N_GRAPHSC * 4, 256);
    float* xc = (float*)w;     w = align_up(w + (size_t)N_GRAPHSC * 3 * HIDC * 4, 256);
    float* hmid = (float*)w;   w = align_up(w + (size_t)N_GRAPHSC * HIDC * 4, 256);
    unsigned short* W2lT = (unsigned short*)w; w = align_up(w + (size_t)HIDC * HIDC * 2, 256);
    unsigned short* W2rT = (unsigned short*)w; w = align_up(w + (size_t)HIDC * HIDC * 2, 256);
    unsigned short* W3lT = (unsigned short*)w; w = align_up(w + (size_t)HIDC * HIDC * 2, 256);
    unsigned short* W3rT = (unsigned short*)w; w = align_up(w + (size_t)HIDC * HIDC * 2, 256);
    char* aggU = w;            w = align_up(w + (size_t)N * HIDC * 2, 256);
    unsigned short* h1 = (unsigned short*)w;  w = align_up(w + (size_t)N * HIDC * 2, 256);
    unsigned short* h2 = (unsigned short*)w;  w = align_up(w + (size_t)N * HIDC * 2 + 65536, 256);
    size_t required = (size_t)(w - w0);
    if (ws_size < required) return;

    float* agg25 = (float*)aggU;
    unsigned short* aggH = (unsigned short*)aggU;
    // transient aliases (dead before their host buffers are first written):
    int* hist = (int*)aggU;            // NCH*NBKT ints = 625 KB, dead after bucket_scatter
    int2* pairs = (int2*)h2;           // E*8B = 12.8 MB, dead after bucket_csrfill

    const int nbN = (N + 255) / 256;
    const dim3 gemm_grid_f32((N + 63) / 64, HIDC / 64);
    const dim3 tgrid(16, 16);
    const dim3 pgrid(N_GRAPHSC, 8);

    // weight transposes
    wtransT<<<tgrid, 256, 0, stream>>>(W2l, W2lT);
    wtransT<<<tgrid, 256, 0, stream>>>(W2r, W2rT);
    wtransT<<<tgrid, 256, 0, stream>>>(W3l, W3lT);
    wtransT<<<tgrid, 256, 0, stream>>>(W3r, W3rT);

    // ---- bucketed CSR build ----
    hist_kernel<<<NCH, 256, 0, stream>>>(dst, hist);
    scan_hist<<<1, 512, 0, stream>>>(hist, bbase);
    bucket_scatter<<<NCH, 256, 0, stream>>>(src, dst, hist, pairs);
    bucket_deg<<<NBKT, 256, 0, stream>>>(pairs, bbase, cnt);
    inv_kernel<<<nbN, 256, 0, stream>>>(cnt, invc, N);
    scan_partial<<<SCAN_NBLK, SCAN_BLK, 0, stream>>>(cnt, row_ofs, bsum);
    scan_bsums<<<1, 128, 0, stream>>>(bsum);
    scan_add<<<SCAN_NBLK, SCAN_BLK, 0, stream>>>(row_ofs, bsum);
    bucket_csrfill<<<NBKT, 256, 0, stream>>>(pairs, bbase, row_ofs, csr);

    // graph ranges + zero xc (pool uses atomicMax over non-negative floats)
    fill_u32<<<1, 256, 0, stream>>>((unsigned*)gstart, (unsigned)N, N_GRAPHSC);
    fill_u32<<<1, 256, 0, stream>>>((unsigned*)gend, 0u, N_GRAPHSC);
    ranges_bounds<<<nbN, 256, 0, stream>>>(batch, gstart, gend, N);
    fill_u32<<<(N_GRAPHSC * 3 * HIDC + 255) / 256, 256, 0, stream>>>((unsigned*)xc, 0u,
                                                                     N_GRAPHSC * 3 * HIDC);

    // ---- layer 1 (K=25, f32) ----
    gather25<<<(N * 32 + 255) / 256, 256, 0, stream>>>(x, row_ofs, csr, invc, agg25);
    sage_gemm_f32<IN_DIMC><<<gemm_grid_f32, 256, 0, stream>>>(agg25, x, W1l, W1r, b1, h1, N);
    pool_max<<<pgrid, 256, 0, stream>>>(h1, gstart, gend, xc, 0);

    // ---- layer 2 (MFMA, gload_lds) ----
    gather256<<<(N * 64 + 255) / 256, 256, 0, stream>>>(h1, row_ofs, csr, invc, aggH);
    sage_gemm_mfma<<<NRB64, 256, 0, stream>>>(aggH, h1, W2lT, W2rT, b2, h2, N);
    pool_max<<<pgrid, 256, 0, stream>>>(h2, gstart, gend, xc, HIDC);

    // ---- layer 3 (MFMA, gload_lds) ----
    gather256<<<(N * 64 + 255) / 256, 256, 0, stream>>>(h2, row_ofs, csr, invc, aggH);
    sage_gemm_mfma<<<NRB64, 256, 0, stream>>>(aggH, h2, W3lT, W3rT, b3, h1, N);
    pool_max<<<pgrid, 256, 0, stream>>>(h1, gstart, gend, xc, 2 * HIDC);

    // ---- head ----
    mlp1<<<N_GRAPHSC, 256, 0, stream>>>(xc, Wlin1, blin1, hmid);
    mlp2<<<N_GRAPHSC, 128, 0, stream>>>(hmid, Wlin2, blin2, out);
}

// Round 13
// 651.803 us; speedup vs baseline: 1.9939x; 1.0318x over previous
//
#include <hip/hip_runtime.h>
#include <hip/hip_bf16.h>

#define N_NODESC 100000
#define N_EDGESC 1600000
#define N_GRAPHSC 200
#define IN_DIMC 25
#define HIDC 256
#define OUT_DIMC 128
#define SCAN_BLK 1024
#define SCAN_NBLK ((N_NODESC + SCAN_BLK - 1) / SCAN_BLK)
#define NRB64 ((N_NODESC + 63) / 64)  // 1563 row-blocks
#define NBKT ((N_NODESC + 255) / 256)  // 391 dst-buckets (256 nodes each)
#define NCH 400                        // edge chunks
#define CHSZ (N_EDGESC / NCH)          // 4000 edges/chunk (exact)

typedef __attribute__((ext_vector_type(8))) short bf16x8;
typedef __attribute__((ext_vector_type(4))) float f32x4;

// ---------- bf16 helpers (raw ushort storage) ----------
__device__ inline float bf2f(unsigned short u) {
    union { float f; unsigned u32; } c;
    c.u32 = ((unsigned)u) << 16;
    return c.f;
}
__device__ inline unsigned short f2bf(float f) {
    union { float f; unsigned u; } c;
    c.f = f;
    unsigned r = (c.u + 0x7FFFu + ((c.u >> 16) & 1u)) >> 16;  // RNE
    return (unsigned short)r;
}
__device__ inline float u2f(unsigned u) {
    union { unsigned u; float f; } c;
    c.u = u;
    return c.f;
}

// ---------- utility fills ----------
__global__ void fill_u32(unsigned* __restrict__ p, unsigned v, int n) {
    int i = blockIdx.x * 256 + threadIdx.x;
    if (i < n) p[i] = v;
}

__global__ void inv_kernel(const int* __restrict__ cnt, float* __restrict__ inv, int n) {
    int i = blockIdx.x * 256 + threadIdx.x;
    if (i < n) inv[i] = 1.0f / (float)max(cnt[i], 1);
}

// ---------- bucketed CSR build ----------
// Pass A: per-chunk histogram over dst>>8
__global__ __launch_bounds__(256) void hist_kernel(const int* __restrict__ dst,
                                                   int* __restrict__ hist) {
    __shared__ int h[NBKT];
    const int c = blockIdx.x, tid = threadIdx.x;
    for (int t = tid; t < NBKT; t += 256) h[t] = 0;
    __syncthreads();
    const int e0 = c * CHSZ;
    for (int e = e0 + tid; e < e0 + CHSZ; e += 256) atomicAdd(&h[dst[e] >> 8], 1);
    __syncthreads();
    for (int t = tid; t < NBKT; t += 256) hist[c * NBKT + t] = h[t];
}

// Pass B1: per-bucket exclusive scan over its 400 chunk counts (one block per bucket)
__global__ __launch_bounds__(512) void col_scan(int* __restrict__ hist,
                                                int* __restrict__ colsum) {
    __shared__ int sm[512];
    const int b = blockIdx.x, t = threadIdx.x;
    int v = (t < NCH) ? hist[t * NBKT + b] : 0;
    sm[t] = v;
    __syncthreads();
    for (int off = 1; off < 512; off <<= 1) {
        int u = (t >= off) ? sm[t - off] : 0;
        __syncthreads();
        sm[t] += u;
        __syncthreads();
    }
    if (t < NCH) hist[t * NBKT + b] = sm[t] - v;  // chunk-prefix within bucket
    if (t == 511) colsum[b] = sm[511];            // bucket total
}

// Pass B2: exclusive scan over bucket totals -> base[NBKT+1]
__global__ __launch_bounds__(512) void bucket_base_scan(const int* __restrict__ colsum,
                                                        int* __restrict__ base) {
    __shared__ int sm[512];
    const int t = threadIdx.x;
    int v = (t < NBKT) ? colsum[t] : 0;
    sm[t] = v;
    __syncthreads();
    for (int off = 1; off < 512; off <<= 1) {
        int u = (t >= off) ? sm[t - off] : 0;
        __syncthreads();
        sm[t] += u;
        __syncthreads();
    }
    if (t <= NBKT) base[t] = sm[t] - v;
}

// Pass C: scatter (src,dst) pairs bucket-sorted
__global__ __launch_bounds__(256) void bucket_scatter(const int* __restrict__ src,
                                                      const int* __restrict__ dst,
                                                      const int* __restrict__ chpre,
                                                      const int* __restrict__ base,
                                                      int2* __restrict__ pairs) {
    __shared__ int cur[NBKT];
    __shared__ int o2[NBKT];
    const int c = blockIdx.x, tid = threadIdx.x;
    for (int t = tid; t < NBKT; t += 256) {
        cur[t] = 0;
        o2[t] = base[t] + chpre[c * NBKT + t];
    }
    __syncthreads();
    const int e0 = c * CHSZ;
    for (int e = e0 + tid; e < e0 + CHSZ; e += 256) {
        int s = src[e], d = dst[e];
        int b = d >> 8;
        int p = atomicAdd(&cur[b], 1);
        pairs[o2[b] + p] = make_int2(s, d);
    }
}

// Pass D0: per-node degree from bucket-sorted pairs (coalesced output)
__global__ __launch_bounds__(256) void bucket_deg(const int2* __restrict__ pairs,
                                                  const int* __restrict__ base,
                                                  int* __restrict__ cnt) {
    __shared__ int h[256];
    const int b = blockIdx.x, tid = threadIdx.x;
    h[tid] = 0;
    __syncthreads();
    for (int i = base[b] + tid; i < base[b + 1]; i += 256)
        atomicAdd(&h[pairs[i].y & 255], 1);
    __syncthreads();
    int node = b * 256 + tid;
    if (node < N_NODESC) cnt[node] = h[tid];
}

// Pass D1: csr fill, writes confined to one ~16KB window per block
__global__ __launch_bounds__(256) void bucket_csrfill(const int2* __restrict__ pairs,
                                                      const int* __restrict__ base,
                                                      const int* __restrict__ row_ofs,
                                                      int* __restrict__ csr) {
    __shared__ int cur[256];
    __shared__ int ob[256];
    const int b = blockIdx.x, tid = threadIdx.x;
    int node = b * 256 + tid;
    ob[tid] = (node < N_NODESC) ? row_ofs[node] : 0;
    cur[tid] = 0;
    __syncthreads();
    for (int i = base[b] + tid; i < base[b + 1]; i += 256) {
        int2 pr = pairs[i];
        int loc = pr.y & 255;
        int p = atomicAdd(&cur[loc], 1);
        csr[ob[loc] + p] = pr.x;
    }
}

// ---------- hierarchical exclusive scan over cnt[N] -> ofs[N+1] ----------
__global__ __launch_bounds__(SCAN_BLK) void scan_partial(const int* __restrict__ cnt,
                                                         int* __restrict__ ofs,
                                                         int* __restrict__ bsum) {
    __shared__ int sm[SCAN_BLK];
    int i = blockIdx.x * SCAN_BLK + threadIdx.x;
    int v = (i < N_NODESC) ? cnt[i] : 0;
    sm[threadIdx.x] = v;
    __syncthreads();
    for (int off = 1; off < SCAN_BLK; off <<= 1) {
        int t = (threadIdx.x >= off) ? sm[threadIdx.x - off] : 0;
        __syncthreads();
        sm[threadIdx.x] += t;
        __syncthreads();
    }
    if (i < N_NODESC) ofs[i] = sm[threadIdx.x] - v;  // exclusive within block
    if (threadIdx.x == SCAN_BLK - 1) bsum[blockIdx.x] = sm[SCAN_BLK - 1];
}

__global__ __launch_bounds__(128) void scan_bsums(int* __restrict__ bsum) {
    __shared__ int sm[SCAN_NBLK];
    if (threadIdx.x == 0) {
        int run = 0;
        for (int b = 0; b < SCAN_NBLK; ++b) {
            int t = bsum[b];
            sm[b] = run;
            run += t;
        }
        for (int b = 0; b < SCAN_NBLK; ++b) bsum[b] = sm[b];
    }
}

__global__ __launch_bounds__(SCAN_BLK) void scan_add(int* __restrict__ ofs,
                                                     const int* __restrict__ bsum) {
    int i = blockIdx.x * SCAN_BLK + threadIdx.x;
    if (i < N_NODESC) ofs[i] += bsum[blockIdx.x];
    if (i == 0) ofs[N_NODESC] = N_EDGESC;
}

// ---------- graph ranges: boundary scan (batch sorted; no atomics) ----------
__global__ void ranges_bounds(const int* __restrict__ batch, int* __restrict__ gstart,
                              int* __restrict__ gend, int n) {
    int i = blockIdx.x * 256 + threadIdx.x;
    if (i >= n) return;
    int g = batch[i];
    if (i == 0 || batch[i - 1] != g) gstart[g] = i;
    if (i == n - 1 || batch[i + 1] != g) gend[g] = i + 1;
}

// ---------- weight transpose f32[256][256] -> bf16 WT[n][k] ----------
__global__ void wtransT(const float* __restrict__ W, unsigned short* __restrict__ WT) {
    __shared__ float t[16][17];
    int bx = blockIdx.x, by = blockIdx.y;
    int tx = threadIdx.x & 15, ty = threadIdx.x >> 4;
    t[ty][tx] = W[(by * 16 + ty) * HIDC + bx * 16 + tx];
    __syncthreads();
    WT[(size_t)(bx * 16 + ty) * HIDC + by * 16 + tx] = f2bf(t[tx][ty]);
}

// ---------- layer-1 mean gather (f32, 25 channels) ----------
__global__ void gather25(const float* __restrict__ x, const int* __restrict__ ofs,
                         const int* __restrict__ csr, const float* __restrict__ inv,
                         float* __restrict__ agg) {
    int idx = blockIdx.x * 256 + threadIdx.x;
    int node = idx >> 5, c = idx & 31;
    if (node >= N_NODESC || c >= IN_DIMC) return;
    float acc = 0.0f;
    int s = ofs[node], e = ofs[node + 1];
    for (int j = s; j < e; ++j) acc += x[(size_t)csr[j] * IN_DIMC + c];
    agg[(size_t)node * IN_DIMC + c] = acc * inv[node];
}

// ---------- hidden mean gather: one wave/node, half-wave/edge, 8 rows in flight ----------
__global__ void gather256(const unsigned short* __restrict__ h, const int* __restrict__ ofs,
                          const int* __restrict__ csr, const float* __restrict__ inv,
                          unsigned short* __restrict__ agg) {
    long long gtid = (long long)blockIdx.x * 256 + threadIdx.x;
    int node = (int)(gtid >> 6);
    if (node >= N_NODESC) return;
    const int lane = threadIdx.x & 63;
    const int half = lane >> 5;
    const int l = lane & 31;
    const int s = ofs[node], e = ofs[node + 1];

    float a0 = 0, a1 = 0, a2 = 0, a3 = 0, a4 = 0, a5 = 0, a6 = 0, a7 = 0;
    const size_t coff = (size_t)l * 8;

#define ACC8(v)                                                             \
    a0 += u2f(((unsigned)(v).x) << 16); a1 += u2f(((unsigned)(v).x) & 0xffff0000u); \
    a2 += u2f(((unsigned)(v).y) << 16); a3 += u2f(((unsigned)(v).y) & 0xffff0000u); \
    a4 += u2f(((unsigned)(v).z) << 16); a5 += u2f(((unsigned)(v).z) & 0xffff0000u); \
    a6 += u2f(((unsigned)(v).w) << 16); a7 += u2f(((unsigned)(v).w) & 0xffff0000u);

    int j = s + half;
    // unroll x4 per half-wave -> up to 8 independent 512B row reads in flight/wave
    for (; j + 6 < e; j += 8) {
        int sn0 = csr[j];
        int sn1 = csr[j + 2];
        int sn2 = csr[j + 4];
        int sn3 = csr[j + 6];
        int4 v0 = *reinterpret_cast<const int4*>(h + (size_t)sn0 * HIDC + coff);
        int4 v1 = *reinterpret_cast<const int4*>(h + (size_t)sn1 * HIDC + coff);
        int4 v2 = *reinterpret_cast<const int4*>(h + (size_t)sn2 * HIDC + coff);
        int4 v3 = *reinterpret_cast<const int4*>(h + (size_t)sn3 * HIDC + coff);
        ACC8(v0) ACC8(v1) ACC8(v2) ACC8(v3)
    }
    for (; j < e; j += 2) {
        int sn0 = csr[j];
        int4 v0 = *reinterpret_cast<const int4*>(h + (size_t)sn0 * HIDC + coff);
        ACC8(v0)
    }
#undef ACC8

    a0 += __shfl_xor(a0, 32, 64); a1 += __shfl_xor(a1, 32, 64);
    a2 += __shfl_xor(a2, 32, 64); a3 += __shfl_xor(a3, 32, 64);
    a4 += __shfl_xor(a4, 32, 64); a5 += __shfl_xor(a5, 32, 64);
    a6 += __shfl_xor(a6, 32, 64); a7 += __shfl_xor(a7, 32, 64);

    if (half == 0) {
        float sc = inv[node];
        int4 p;
        p.x = (int)((unsigned)f2bf(a0 * sc) | ((unsigned)f2bf(a1 * sc) << 16));
        p.y = (int)((unsigned)f2bf(a2 * sc) | ((unsigned)f2bf(a3 * sc) << 16));
        p.z = (int)((unsigned)f2bf(a4 * sc) | ((unsigned)f2bf(a5 * sc) << 16));
        p.w = (int)((unsigned)f2bf(a6 * sc) | ((unsigned)f2bf(a7 * sc) << 16));
        *reinterpret_cast<int4*>(agg + (size_t)node * HIDC + coff) = p;
    }
}

// ---------- layer-1 f32 SAGE GEMM (K=25) ----------
template <int K>
__global__ __launch_bounds__(256) void sage_gemm_f32(
    const float* __restrict__ agg, const float* __restrict__ h,
    const float* __restrict__ Wl, const float* __restrict__ Wr,
    const float* __restrict__ bias,
    unsigned short* __restrict__ out, int nrows) {
    constexpr int BM = 64, BN = 64, BK = 16;
    __shared__ float sA[BK][BM + 4];
    __shared__ float sB[BK][BN + 4];
    const int tid = threadIdx.x;
    const int tx = tid & 15, ty = tid >> 4;
    const int rowbase = blockIdx.x * BM;
    const int colbase = blockIdx.y * BN;
    float acc[4][4] = {};
    const int lrow = tid >> 2, lkq = (tid & 3) * 4;
    const int lkB = tid >> 4, lnB = (tid & 15) * 4;

    for (int pass = 0; pass < 2; ++pass) {
        const float* __restrict__ A = pass ? h : agg;
        const float* __restrict__ W = pass ? Wr : Wl;
        const int grow = rowbase + lrow;
        for (int kb = 0; kb < K; kb += BK) {
#pragma unroll
            for (int j = 0; j < 4; ++j) {
                int k = kb + lkq + j;
                float v = 0.0f;
                if (grow < nrows && k < K) v = A[(size_t)grow * K + k];
                sA[lkq + j][lrow] = v;
            }
#pragma unroll
            for (int j = 0; j < 4; ++j) {
                int k = kb + lkB;
                int n = colbase + lnB + j;
                sB[lkB][lnB + j] = (k < K) ? W[(size_t)k * HIDC + n] : 0.0f;
            }
            __syncthreads();
#pragma unroll
            for (int kk = 0; kk < BK; ++kk) {
                float a[4], b[4];
#pragma unroll
                for (int i = 0; i < 4; ++i) a[i] = sA[kk][ty * 4 + i];
#pragma unroll
                for (int j = 0; j < 4; ++j) b[j] = sB[kk][tx * 4 + j];
#pragma unroll
                for (int i = 0; i < 4; ++i)
#pragma unroll
                    for (int j = 0; j < 4; ++j) acc[i][j] += a[i] * b[j];
            }
            __syncthreads();
        }
    }
#pragma unroll
    for (int i = 0; i < 4; ++i) {
        int r = rowbase + ty * 4 + i;
        if (r >= nrows) continue;
#pragma unroll
        for (int j = 0; j < 4; ++j) {
            int c = colbase + tx * 4 + j;
            out[(size_t)r * HIDC + c] = f2bf(fmaxf(acc[i][j] + bias[c], 0.0f));
        }
    }
}

// ---------- MFMA bf16 SAGE GEMM, m97-style: global_load_lds + XOR-swizzled LDS ----------
__global__ __launch_bounds__(256) void sage_gemm_mfma(
    const unsigned short* __restrict__ A0, const unsigned short* __restrict__ A1,
    const unsigned short* __restrict__ B0T, const unsigned short* __restrict__ B1T,
    const float* __restrict__ bias, unsigned short* __restrict__ out, int M) {
    constexpr int KD = 256;
    __shared__ unsigned short sA[64 * 64];   // [64 r][64 k] 8KB
    __shared__ unsigned short sB[256 * 64];  // [256 c][64 k] 32KB
    const int rowbase = blockIdx.x * 64;
    const int tid = threadIdx.x;
    const int lane = tid & 63;
    const int w = tid >> 6;  // wave 0..3 = col stripe
    const int fr = lane & 15;
    const int kq8 = (lane >> 4) << 3;  // 0,8,16,24 elems

    const int srow = lane >> 3;            // row within 8-row stripe
    const int schunk = (lane & 7) ^ srow;  // inverse-swizzled source 16B chunk

    f32x4 acc[4][4] = {};

    for (int pass = 0; pass < 2; ++pass) {
        const unsigned short* __restrict__ A = pass ? A1 : A0;
        const unsigned short* __restrict__ BT = pass ? B1T : B0T;
        for (int ks = 0; ks < 4; ++ks) {
            const int kb = ks * 64;
            __syncthreads();  // prior k-step frag reads done before overwrite
#pragma unroll
            for (int c = 0; c < 2; ++c) {
                int ar = w * 16 + c * 8 + srow;
                const unsigned short* g = A + (size_t)(rowbase + ar) * KD + kb + (schunk << 3);
                __builtin_amdgcn_global_load_lds(
                    (const __attribute__((address_space(1))) void*)g,
                    (__attribute__((address_space(3))) void*)(sA + (w * 16 + c * 8) * 64),
                    16, 0, 0);
            }
#pragma unroll
            for (int c = 0; c < 8; ++c) {
                int br = w * 64 + c * 8 + srow;
                const unsigned short* g = BT + (size_t)br * KD + kb + (schunk << 3);
                __builtin_amdgcn_global_load_lds(
                    (const __attribute__((address_space(1))) void*)g,
                    (__attribute__((address_space(3))) void*)(sB + (w * 64 + c * 8) * 64),
                    16, 0, 0);
            }
            __syncthreads();  // vmcnt drained here -> LDS ready
#pragma unroll
            for (int kg = 0; kg < 2; ++kg) {
                bf16x8 af[4], bfr[4];
#pragma unroll
                for (int t = 0; t < 4; ++t) {
                    int ra = t * 16 + fr;
                    int ba = ra * 128 + ((kg * 64 + kq8 * 2) ^ ((ra & 7) << 4));
                    af[t] = *reinterpret_cast<const bf16x8*>(
                        reinterpret_cast<const char*>(sA) + ba);
                    int rb = w * 64 + t * 16 + fr;
                    int bb2 = rb * 128 + ((kg * 64 + kq8 * 2) ^ ((rb & 7) << 4));
                    bfr[t] = *reinterpret_cast<const bf16x8*>(
                        reinterpret_cast<const char*>(sB) + bb2);
                }
#pragma unroll
                for (int i = 0; i < 4; ++i)
#pragma unroll
                    for (int j = 0; j < 4; ++j)
                        acc[i][j] = __builtin_amdgcn_mfma_f32_16x16x32_bf16(
                            af[i], bfr[j], acc[i][j], 0, 0, 0);
            }
        }
    }

    const int crow0 = (lane >> 4) << 2;
#pragma unroll
    for (int i = 0; i < 4; ++i) {
#pragma unroll
        for (int j = 0; j < 4; ++j) {
            int col = w * 64 + j * 16 + fr;
            float bb = bias[col];
#pragma unroll
            for (int r = 0; r < 4; ++r) {
                int row = rowbase + i * 16 + crow0 + r;
                if (row < M)
                    out[(size_t)row * HIDC + col] = f2bf(fmaxf(acc[i][j][r] + bb, 0.0f));
            }
        }
    }
}

// ---------- segment-max pool: 8-way parallel per graph, atomicMax (values >= 0) ----------
__global__ void pool_max(const unsigned short* __restrict__ h, const int* __restrict__ gstart,
                         const int* __restrict__ gend, float* __restrict__ xc, int col_off) {
    int g = blockIdx.x;
    int chunk = blockIdx.y;  // 0..7
    int c = threadIdx.x;
    int s = gstart[g], e = gend[g];
    int len = e - s;
    if (len <= 0) return;
    int per = (len + 7) >> 3;
    int cs = s + chunk * per;
    int ce = min(cs + per, e);
    if (cs >= ce) return;
    float m = 0.0f;  // relu outputs >= 0
    for (int i = cs; i < ce; ++i) m = fmaxf(m, bf2f(h[(size_t)i * HIDC + c]));
    atomicMax(reinterpret_cast<int*>(&xc[(size_t)g * (3 * HIDC) + col_off + c]),
              __float_as_int(m));
}

// ---------- head MLPs ----------
__global__ void mlp1(const float* __restrict__ xc, const float* __restrict__ W,
                     const float* __restrict__ b, float* __restrict__ hmid) {
    __shared__ float row[3 * HIDC];
    int g = blockIdx.x;
    for (int i = threadIdx.x; i < 3 * HIDC; i += 256) row[i] = xc[(size_t)g * (3 * HIDC) + i];
    __syncthreads();
    float acc = b[threadIdx.x];
    for (int k = 0; k < 3 * HIDC; ++k) acc += row[k] * W[(size_t)k * HIDC + threadIdx.x];
    hmid[(size_t)g * HIDC + threadIdx.x] = fmaxf(acc, 0.0f);
}

__global__ void mlp2(const float* __restrict__ hmid, const float* __restrict__ W,
                     const float* __restrict__ b, float* __restrict__ out) {
    __shared__ float row[HIDC];
    int g = blockIdx.x;
    for (int i = threadIdx.x; i < HIDC; i += 128) row[i] = hmid[(size_t)g * HIDC + i];
    __syncthreads();
    float acc = b[threadIdx.x];
    for (int k = 0; k < HIDC; ++k) acc += row[k] * W[(size_t)k * OUT_DIMC + threadIdx.x];
    out[(size_t)g * OUT_DIMC + threadIdx.x] = acc;
}

static inline char* align_up(char* p, size_t a) {
    return (char*)(((uintptr_t)p + a - 1) & ~(uintptr_t)(a - 1));
}

extern "C" void kernel_launch(void* const* d_in, const int* in_sizes, int n_in,
                              void* d_out, int out_size, void* d_ws, size_t ws_size,
                              hipStream_t stream) {
    const float* x = (const float*)d_in[0];
    const int* edge_index = (const int*)d_in[1];
    const int* batch = (const int*)d_in[2];
    const float* W1l = (const float*)d_in[3];
    const float* W1r = (const float*)d_in[4];
    const float* b1 = (const float*)d_in[5];
    const float* W2l = (const float*)d_in[6];
    const float* W2r = (const float*)d_in[7];
    const float* b2 = (const float*)d_in[8];
    const float* W3l = (const float*)d_in[9];
    const float* W3r = (const float*)d_in[10];
    const float* b3 = (const float*)d_in[11];
    const float* Wlin1 = (const float*)d_in[12];
    const float* blin1 = (const float*)d_in[13];
    const float* Wlin2 = (const float*)d_in[14];
    const float* blin2 = (const float*)d_in[15];
    float* out = (float*)d_out;

    const int N = N_NODESC, E = N_EDGESC;
    const int* src = edge_index;
    const int* dst = edge_index + E;

    // ---- workspace carve-up ----
    char* w0 = (char*)d_ws;
    char* w = w0;
    int* cnt = (int*)w;        w = align_up(w + (size_t)N * 4, 256);
    float* invc = (float*)w;   w = align_up(w + (size_t)N * 4, 256);
    int* row_ofs = (int*)w;    w = align_up(w + (size_t)(N + 1) * 4, 256);
    int* bsum = (int*)w;       w = align_up(w + (size_t)SCAN_NBLK * 4, 256);
    int* bbase = (int*)w;      w = align_up(w + (size_t)(NBKT + 1) * 4, 256);
    int* colsum = (int*)w;     w = align_up(w + (size_t)NBKT * 4, 256);
    int* csr = (int*)w;        w = align_up(w + (size_t)E * 4, 256);
    int* gstart = (int*)w;     w = align_up(w + (size_t)N_GRAPHSC * 4, 256);
    int* gend = (int*)w;       w = align_up(w + (size_t)N_GRAPHSC * 4, 256);
    float* xc = (float*)w;     w = align_up(w + (size_t)N_GRAPHSC * 3 * HIDC * 4, 256);
    float* hmid = (float*)w;   w = align_up(w + (size_t)N_GRAPHSC * HIDC * 4, 256);
    unsigned short* W2lT = (unsigned short*)w; w = align_up(w + (size_t)HIDC * HIDC * 2, 256);
    unsigned short* W2rT = (unsigned short*)w; w = align_up(w + (size_t)HIDC * HIDC * 2, 256);
    unsigned short* W3lT = (unsigned short*)w; w = align_up(w + (size_t)HIDC * HIDC * 2, 256);
    unsigned short* W3rT = (unsigned short*)w; w = align_up(w + (size_t)HIDC * HIDC * 2, 256);
    char* aggU = w;            w = align_up(w + (size_t)N * HIDC * 2, 256);
    unsigned short* h1 = (unsigned short*)w;  w = align_up(w + (size_t)N * HIDC * 2, 256);
    unsigned short* h2 = (unsigned short*)w;  w = align_up(w + (size_t)N * HIDC * 2 + 65536, 256);
    size_t required = (size_t)(w - w0);
    if (ws_size < required) return;

    float* agg25 = (float*)aggU;
    unsigned short* aggH = (unsigned short*)aggU;
    // transient aliases (dead before their host buffers are first written):
    int* hist = (int*)aggU;   // NCH*NBKT ints = 625 KB, dead after bucket_scatter
    int2* pairs = (int2*)h2;  // E*8B = 12.8 MB, dead after bucket_csrfill

    const int nbN = (N + 255) / 256;
    const dim3 gemm_grid_f32((N + 63) / 64, HIDC / 64);
    const dim3 tgrid(16, 16);
    const dim3 pgrid(N_GRAPHSC, 8);

    // weight transposes
    wtransT<<<tgrid, 256, 0, stream>>>(W2l, W2lT);
    wtransT<<<tgrid, 256, 0, stream>>>(W2r, W2rT);
    wtransT<<<tgrid, 256, 0, stream>>>(W3l, W3lT);
    wtransT<<<tgrid, 256, 0, stream>>>(W3r, W3rT);

    // ---- bucketed CSR build ----
    hist_kernel<<<NCH, 256, 0, stream>>>(dst, hist);
    col_scan<<<NBKT, 512, 0, stream>>>(hist, colsum);
    bucket_base_scan<<<1, 512, 0, stream>>>(colsum, bbase);
    bucket_scatter<<<NCH, 256, 0, stream>>>(src, dst, hist, bbase, pairs);
    bucket_deg<<<NBKT, 256, 0, stream>>>(pairs, bbase, cnt);
    inv_kernel<<<nbN, 256, 0, stream>>>(cnt, invc, N);
    scan_partial<<<SCAN_NBLK, SCAN_BLK, 0, stream>>>(cnt, row_ofs, bsum);
    scan_bsums<<<1, 128, 0, stream>>>(bsum);
    scan_add<<<SCAN_NBLK, SCAN_BLK, 0, stream>>>(row_ofs, bsum);
    bucket_csrfill<<<NBKT, 256, 0, stream>>>(pairs, bbase, row_ofs, csr);

    // graph ranges + zero xc (pool uses atomicMax over non-negative floats)
    fill_u32<<<1, 256, 0, stream>>>((unsigned*)gstart, (unsigned)N, N_GRAPHSC);
    fill_u32<<<1, 256, 0, stream>>>((unsigned*)gend, 0u, N_GRAPHSC);
    ranges_bounds<<<nbN, 256, 0, stream>>>(batch, gstart, gend, N);
    fill_u32<<<(N_GRAPHSC * 3 * HIDC + 255) / 256, 256, 0, stream>>>((unsigned*)xc, 0u,
                                                                     N_GRAPHSC * 3 * HIDC);

    // ---- layer 1 (K=25, f32) ----
    gather25<<<(N * 32 + 255) / 256, 256, 0, stream>>>(x, row_ofs, csr, invc, agg25);
    sage_gemm_f32<IN_DIMC><<<gemm_grid_f32, 256, 0, stream>>>(agg25, x, W1l, W1r, b1, h1, N);
    pool_max<<<pgrid, 256, 0, stream>>>(h1, gstart, gend, xc, 0);

    // ---- layer 2 (MFMA, gload_lds) ----
    gather256<<<(N * 64 + 255) / 256, 256, 0, stream>>>(h1, row_ofs, csr, invc, aggH);
    sage_gemm_mfma<<<NRB64, 256, 0, stream>>>(aggH, h1, W2lT, W2rT, b2, h2, N);
    pool_max<<<pgrid, 256, 0, stream>>>(h2, gstart, gend, xc, HIDC);

    // ---- layer 3 (MFMA, gload_lds) ----
    gather256<<<(N * 64 + 255) / 256, 256, 0, stream>>>(h2, row_ofs, csr, invc, aggH);
    sage_gemm_mfma<<<NRB64, 256, 0, stream>>>(aggH, h2, W3lT, W3rT, b3, h1, N);
    pool_max<<<pgrid, 256, 0, stream>>>(h1, gstart, gend, xc, 2 * HIDC);

    // ---- head ----
    mlp1<<<N_GRAPHSC, 256, 0, stream>>>(xc, Wlin1, blin1, hmid);
    mlp2<<<N_GRAPHSC, 128, 0, stream>>>(hmid, Wlin2, blin2, out);
}